// Round 5
// baseline (6759.188 us; speedup 1.0000x reference)
//
#include <hip/hip_runtime.h>
#include <hip/hip_bf16.h>
#include <hip/hip_fp16.h>

// Problem constants
#define N_NODES 50000
#define N_EDGES 500000
#define IN_CH   128
#define D       256   // HEADS * OUT_CH
#define UDIM    512   // HEADS * 128 (u and y width)
#define OUT_CH  64
#define HEADS   4
#define NC      49    // scan chunks of 1024: ceil(50000/1024)

// ---------------------------------------------------------------------------
// init: zero histogram counters and softmax denominators
// ---------------------------------------------------------------------------
__global__ __launch_bounds__(256) void init_kernel(int* __restrict__ cnt,
                                                   double* __restrict__ S) {
    int i = blockIdx.x * 256 + threadIdx.x;
    if (i < N_NODES) cnt[i] = 0;
    if (i < HEADS) S[i] = 0.0;
}

// ---------------------------------------------------------------------------
// x16 = fp16 copy of x (edge-kernel gather payload: 256 B/row instead of 512)
// ---------------------------------------------------------------------------
__global__ __launch_bounds__(256) void x16_kernel(const float* __restrict__ x,
                                                  __half* __restrict__ x16) {
    int i = (blockIdx.x * 256 + threadIdx.x) * 4;
    if (i < N_NODES * IN_CH) {
        float4 v = *(const float4*)(x + i);
        union { __half2 h[2]; uint2 u; } pk;
        pk.h[0] = __floats2half2_rn(v.x, v.y);
        pk.h[1] = __floats2half2_rn(v.z, v.w);
        *(uint2*)(x16 + i) = pk.u;
    }
}

// ---------------------------------------------------------------------------
// M[i][h*128+j] = sum_c Wq[i][h*64+c] * Wk[j][h*64+c]   (one block per head)
// ---------------------------------------------------------------------------
__global__ __launch_bounds__(256) void mbuild_kernel(const float* __restrict__ Wq,
                                                     const float* __restrict__ Wk,
                                                     float* __restrict__ M) {
    const int h = blockIdx.x;
    const int tid = threadIdx.x;
    __shared__ float ks[128][64];
    for (int i = tid; i < 128 * 64; i += 256) {
        int r = i >> 6, c = i & 63;
        ks[r][c] = Wk[(size_t)r * D + h * 64 + c];
    }
    __syncthreads();
    const int i = tid >> 1;
    const int j0 = (tid & 1) * 64;
    float q[64];
    #pragma unroll 16
    for (int c = 0; c < 64; ++c) q[c] = Wq[(size_t)i * D + h * 64 + c];
    for (int jj = 0; jj < 64; ++jj) {
        int j = j0 + jj;
        float s = 0.f;
        #pragma unroll 16
        for (int c = 0; c < 64; ++c) s += q[c] * ks[j][c];
        M[(size_t)i * UDIM + h * 128 + j] = s;
    }
}

// ---------------------------------------------------------------------------
// Zc[(h*128+i)*64 + c] = sum_j Wv[i][h*64+j] * Wout[(h*64+j)][c]
// ---------------------------------------------------------------------------
__global__ __launch_bounds__(256) void zbuild_kernel(const float* __restrict__ Wv,
                                                     const float* __restrict__ Wout,
                                                     float* __restrict__ Zc) {
    int h = blockIdx.x;
    int tid = threadIdx.x;
    __shared__ float wo[64 * 64];
    for (int i = tid; i < 64 * 64; i += 256) {
        int j = i >> 6, c = i & 63;
        wo[i] = Wout[(h * 64 + j) * OUT_CH + c];
    }
    __syncthreads();
    int c = tid & 63, i0 = tid >> 6;
    for (int i = i0; i < IN_CH; i += 4) {
        float s = 0.f;
        const float* wv = Wv + (size_t)i * D + h * 64;
        #pragma unroll 8
        for (int j = 0; j < 64; ++j) s += wv[j] * wo[j * 64 + c];
        Zc[(size_t)(h * 128 + i) * OUT_CH + c] = s;
    }
}

// ---------------------------------------------------------------------------
// GEMM1: u16 = half(x[50000x128] @ M[128x512]).  BM=BN=128, BK=32, 8x8 tile.
// XOR-swizzled As (conflict-free), register prefetch of next k-tile so global
// loads stay in flight across barriers (plain loads: no vmcnt drain at barrier).
// ---------------------------------------------------------------------------
__global__ __launch_bounds__(256) void gemm_u_kernel(const float* __restrict__ x,
                                                     const float* __restrict__ M,
                                                     __half* __restrict__ u16) {
    __shared__ float As[32][128];
    __shared__ float Bs[32][128];

    const int bm = blockIdx.x;
    const int colbase = blockIdx.y * 128;   // 0..3
    const int m0 = bm * 128;
    const int tid = threadIdx.x;
    const int tx = tid & 15, ty = tid >> 4;

    float acc[8][8];
    #pragma unroll
    for (int i = 0; i < 8; ++i)
        #pragma unroll
        for (int j = 0; j < 8; ++j) acc[i][j] = 0.f;

    auto load_tiles = [&](int kt, float4* px, float4* pm) {
        const int k0 = kt * 32;
        #pragma unroll
        for (int r = 0; r < 4; ++r) {
            int f = tid + r * 256;
            int m = f >> 3, k4 = (f & 7) << 2;
            px[r] = make_float4(0.f, 0.f, 0.f, 0.f);
            if (m0 + m < N_NODES)
                px[r] = *(const float4*)(x + (size_t)(m0 + m) * IN_CH + k0 + k4);
        }
        #pragma unroll
        for (int r = 0; r < 4; ++r) {
            int f = tid + r * 256;
            int kb = f >> 5, n4 = (f & 31) << 2;
            pm[r] = *(const float4*)(M + (size_t)(k0 + kb) * UDIM + colbase + n4);
        }
    };

    float4 px[4], pm[4];
    load_tiles(0, px, pm);

    #pragma unroll
    for (int kt = 0; kt < 4; ++kt) {
        // stage current regs -> LDS
        #pragma unroll
        for (int r = 0; r < 4; ++r) {
            int f = tid + r * 256;
            int m = f >> 3, k4 = (f & 7) << 2;
            const int sc = m ^ k4;
            As[k4 + 0][sc] = px[r].x; As[k4 + 1][sc] = px[r].y;
            As[k4 + 2][sc] = px[r].z; As[k4 + 3][sc] = px[r].w;
        }
        #pragma unroll
        for (int r = 0; r < 4; ++r) {
            int f = tid + r * 256;
            int kb = f >> 5, n4 = (f & 31) << 2;
            *(float4*)&Bs[kb][n4] = pm[r];
        }
        float4 nx[4], nm[4];
        if (kt < 3) load_tiles(kt + 1, nx, nm);   // in flight during compute
        __syncthreads();
        #pragma unroll
        for (int kk = 0; kk < 32; ++kk) {
            const int sw = kk & 28;
            float a[8], b[8];
            *(float4*)(a)     = *(float4*)&As[kk][(ty * 4) ^ sw];
            *(float4*)(a + 4) = *(float4*)&As[kk][(64 + ty * 4) ^ sw];
            *(float4*)(b)     = *(float4*)&Bs[kk][tx * 4];
            *(float4*)(b + 4) = *(float4*)&Bs[kk][64 + tx * 4];
            #pragma unroll
            for (int i = 0; i < 8; ++i)
                #pragma unroll
                for (int j = 0; j < 8; ++j)
                    acc[i][j] += a[i] * b[j];
        }
        __syncthreads();
        if (kt < 3) {
            #pragma unroll
            for (int r = 0; r < 4; ++r) { px[r] = nx[r]; pm[r] = nm[r]; }
        }
    }
    #pragma unroll
    for (int i = 0; i < 8; ++i) {
        int row = (i < 4) ? (ty * 4 + i) : (64 + ty * 4 + (i - 4));
        int m = m0 + row;
        if (m < N_NODES) {
            __half* dst = u16 + (size_t)m * UDIM + colbase;
            union { __half2 h[2]; uint2 u; } p0, p1;
            p0.h[0] = __floats2half2_rn(acc[i][0], acc[i][1]);
            p0.h[1] = __floats2half2_rn(acc[i][2], acc[i][3]);
            p1.h[0] = __floats2half2_rn(acc[i][4], acc[i][5]);
            p1.h[1] = __floats2half2_rn(acc[i][6], acc[i][7]);
            *(uint2*)(dst + tx * 4)      = p0.u;
            *(uint2*)(dst + 64 + tx * 4) = p1.u;
        }
    }
}

// ---------------------------------------------------------------------------
// counting sort by tgt: histogram -> 3-phase scan -> scatter payload {src,w}
// ---------------------------------------------------------------------------
__global__ __launch_bounds__(256) void hist_kernel(const int* __restrict__ ei,
                                                   int* __restrict__ cnt) {
    int e = blockIdx.x * 256 + threadIdx.x;
    if (e < N_EDGES) atomicAdd(&cnt[ei[N_EDGES + e]], 1);
}

__global__ __launch_bounds__(256) void scan_reduce_kernel(const int* __restrict__ cnt,
                                                          int* __restrict__ csum) {
    const int b = blockIdx.x, tid = threadIdx.x;
    const int lane = tid & 63, wid = tid >> 6;
    int s = 0;
    int idx0 = b * 1024 + tid * 4;
    #pragma unroll
    for (int i = 0; i < 4; ++i) {
        int idx = idx0 + i;
        if (idx < N_NODES) s += cnt[idx];
    }
    #pragma unroll
    for (int m = 1; m < 64; m <<= 1) s += __shfl_xor(s, m, 64);
    __shared__ int w[4];
    if (lane == 0) w[wid] = s;
    __syncthreads();
    if (tid == 0) csum[b] = w[0] + w[1] + w[2] + w[3];
}

__global__ __launch_bounds__(64) void scan_top_kernel(int* __restrict__ csum) {
    int lane = threadIdx.x;
    int v = (lane < NC) ? csum[lane] : 0;
    int x = v;
    #pragma unroll
    for (int d = 1; d < 64; d <<= 1) {
        int y = __shfl_up(x, d, 64);
        if (lane >= d) x += y;
    }
    if (lane < NC) csum[lane] = x - v;   // exclusive
}

__global__ __launch_bounds__(256) void scan_chunks_kernel(int* __restrict__ cnt,
                                                          const int* __restrict__ csum,
                                                          int* __restrict__ rp) {
    const int b = blockIdx.x, tid = threadIdx.x;
    const int lane = tid & 63, wid = tid >> 6;
    __shared__ int wsum[4];
    int v[4];
    const int idx0 = b * 1024 + tid * 4;
    #pragma unroll
    for (int i = 0; i < 4; ++i) {
        int idx = idx0 + i;
        v[i] = (idx < N_NODES) ? cnt[idx] : 0;
    }
    int tsum = v[0] + v[1] + v[2] + v[3];
    int x = tsum;
    #pragma unroll
    for (int d = 1; d < 64; d <<= 1) {
        int y = __shfl_up(x, d, 64);
        if (lane >= d) x += y;
    }
    if (lane == 63) wsum[wid] = x;
    __syncthreads();
    int woff = 0;
    for (int w = 0; w < wid; ++w) woff += wsum[w];
    int excl = csum[b] + woff + x - tsum;
    #pragma unroll
    for (int i = 0; i < 4; ++i) {
        int idx = idx0 + i;
        if (idx < N_NODES) { rp[idx] = excl; cnt[idx] = excl; }
        excl += v[i];
    }
}

__global__ __launch_bounds__(256) void scatter_kernel(const int* __restrict__ ei,
                                                      const float* __restrict__ ew,
                                                      int* __restrict__ cnt,
                                                      int2* __restrict__ payload) {
    int e = blockIdx.x * 256 + threadIdx.x;
    if (e >= N_EDGES) return;
    int s = ei[e], t = ei[N_EDGES + e];
    int pos = atomicAdd(&cnt[t], 1);
    payload[pos] = make_int2(s, __float_as_int(ew[e]));
}

// ---------------------------------------------------------------------------
// Fused edge kernel: per tgt node (16 lanes), loop incoming edges:
//   gather x16_s (256 B), d_h = u_t . x_s (shfl-16), p = exp(leaky(...)),
//   y_h += p_h * x_s (fp32 regs) -> y16. Accumulate S[h] (double).
// ---------------------------------------------------------------------------
__global__ __launch_bounds__(256) void edge_fused_kernel(const __half* __restrict__ u16,
                                                         const __half* __restrict__ x16,
                                                         const int* __restrict__ rp,
                                                         const int* __restrict__ cnt,
                                                         const int2* __restrict__ payload,
                                                         const float* __restrict__ We,
                                                         __half* __restrict__ y16,
                                                         double* __restrict__ S) {
    const int tid = threadIdx.x;
    const int j = tid & 15;
    const int node = blockIdx.x * 16 + (tid >> 4);
    const float4 we = *(const float4*)We;
    const float wev[4] = {we.x, we.y, we.z, we.w};

    // u[node] fragment: lane j holds, per head h, halves [h*128 + j*8 .. +7]
    const __half* ur = u16 + (size_t)node * UDIM;
    float4 ua[4], ub[4], ya[4], yb[4];
    #pragma unroll
    for (int h = 0; h < 4; ++h) {
        uint4 raw = *(const uint4*)(ur + h * 128 + j * 8);
        const __half2* hp = (const __half2*)&raw;
        float2 f0 = __half22float2(hp[0]), f1 = __half22float2(hp[1]);
        float2 f2 = __half22float2(hp[2]), f3 = __half22float2(hp[3]);
        ua[h] = make_float4(f0.x, f0.y, f1.x, f1.y);
        ub[h] = make_float4(f2.x, f2.y, f3.x, f3.y);
        ya[h] = make_float4(0.f, 0.f, 0.f, 0.f);
        yb[h] = make_float4(0.f, 0.f, 0.f, 0.f);
    }

    float sacc[4] = {0.f, 0.f, 0.f, 0.f};
    const int start = rp[node];
    const int end = cnt[node];
    int2 pl = (start < end) ? payload[start] : make_int2(0, 0);
    for (int e = start; e < end; ++e) {
        int2 plnext = (e + 1 < end) ? payload[e + 1] : pl;   // software pipeline
        const int s = pl.x;
        const float w = __int_as_float(pl.y);
        uint4 raw = *(const uint4*)(x16 + (size_t)s * IN_CH + j * 8);
        const __half2* hp = (const __half2*)&raw;
        float2 f0 = __half22float2(hp[0]), f1 = __half22float2(hp[1]);
        float2 f2 = __half22float2(hp[2]), f3 = __half22float2(hp[3]);
        float4 xa = make_float4(f0.x, f0.y, f1.x, f1.y);
        float4 xb = make_float4(f2.x, f2.y, f3.x, f3.y);
        float d[4];
        #pragma unroll
        for (int h = 0; h < 4; ++h) {
            d[h] = ua[h].x * xa.x + ua[h].y * xa.y + ua[h].z * xa.z + ua[h].w * xa.w
                 + ub[h].x * xb.x + ub[h].y * xb.y + ub[h].z * xb.z + ub[h].w * xb.w;
        }
        #pragma unroll
        for (int m = 1; m < 16; m <<= 1) {
            #pragma unroll
            for (int h = 0; h < 4; ++h) d[h] += __shfl_xor(d[h], m, 16);
        }
        float p[4];
        #pragma unroll
        for (int h = 0; h < 4; ++h) {
            float l = d[h] * 0.125f + w * wev[h];
            l = (l > 0.f) ? l : 0.2f * l;
            p[h] = __expf(l);
        }
        #pragma unroll
        for (int h = 0; h < 4; ++h) {
            ya[h].x += p[h] * xa.x; ya[h].y += p[h] * xa.y;
            ya[h].z += p[h] * xa.z; ya[h].w += p[h] * xa.w;
            yb[h].x += p[h] * xb.x; yb[h].y += p[h] * xb.y;
            yb[h].z += p[h] * xb.z; yb[h].w += p[h] * xb.w;
        }
        if (j == 0) {
            sacc[0] += p[0]; sacc[1] += p[1]; sacc[2] += p[2]; sacc[3] += p[3];
        }
        pl = plnext;
    }
    // write y16 fragment
    __half* yr = y16 + (size_t)node * UDIM;
    #pragma unroll
    for (int h = 0; h < 4; ++h) {
        union { __half2 hh[4]; uint4 u; } pk;
        pk.hh[0] = __floats2half2_rn(ya[h].x, ya[h].y);
        pk.hh[1] = __floats2half2_rn(ya[h].z, ya[h].w);
        pk.hh[2] = __floats2half2_rn(yb[h].x, yb[h].y);
        pk.hh[3] = __floats2half2_rn(yb[h].z, yb[h].w);
        *(uint4*)(yr + h * 128 + j * 8) = pk.u;
    }
    __shared__ float sblk[4];
    if (tid < 4) sblk[tid] = 0.f;
    __syncthreads();
    if (j == 0) {
        atomicAdd(&sblk[0], sacc[0]);
        atomicAdd(&sblk[1], sacc[1]);
        atomicAdd(&sblk[2], sacc[2]);
        atomicAdd(&sblk[3], sacc[3]);
    }
    __syncthreads();
    if (tid < 4) atomicAdd(&S[tid], (double)sblk[tid]);
}

// ---------------------------------------------------------------------------
// GEMM2: out = (y16 scaled by 1/S per head) @ Zc[512,64] + b_out
// BM=128, BN=64, BK=32, 8x4 microtile, register prefetch, swizzled As.
// ---------------------------------------------------------------------------
__global__ __launch_bounds__(256) void gemm_out_kernel(const __half* __restrict__ y16,
                                                       const float* __restrict__ Zc,
                                                       const double* __restrict__ S,
                                                       const float* __restrict__ b_out,
                                                       float* __restrict__ out) {
    __shared__ float As[32][128];
    __shared__ float Bs[32][64];
    __shared__ float invs[4];

    const int m0 = blockIdx.x * 128;
    const int tid = threadIdx.x;
    const int tx = tid & 15, ty = tid >> 4;

    if (tid < 4) invs[tid] = (float)(1.0 / S[tid]);
    __syncthreads();

    float acc[8][4];
    #pragma unroll
    for (int i = 0; i < 8; ++i)
        #pragma unroll
        for (int jj = 0; jj < 4; ++jj) acc[i][jj] = 0.f;

    auto load_tiles = [&](int kt, uint4* py, float4* pz) {
        const int k0 = kt * 32;
        #pragma unroll
        for (int r = 0; r < 2; ++r) {
            int f = tid + r * 256;
            int m = f >> 2, k8 = (f & 3) << 3;
            py[r] = make_uint4(0u, 0u, 0u, 0u);
            if (m0 + m < N_NODES)
                py[r] = *(const uint4*)(y16 + (size_t)(m0 + m) * UDIM + k0 + k8);
        }
        #pragma unroll
        for (int r = 0; r < 2; ++r) {
            int f = tid + r * 256;
            int kb = f >> 4, n4 = (f & 15) << 2;
            pz[r] = *(const float4*)(Zc + (size_t)(k0 + kb) * OUT_CH + n4);
        }
    };

    uint4 py[2]; float4 pz[2];
    load_tiles(0, py, pz);

    for (int kt = 0; kt < 16; ++kt) {
        const float sc0 = invs[kt >> 2];   // 32-k tile within one head (128k/head)
        #pragma unroll
        for (int r = 0; r < 2; ++r) {
            int f = tid + r * 256;
            int m = f >> 2, k8 = (f & 3) << 3;
            const __half2* hp = (const __half2*)&py[r];
            #pragma unroll
            for (int c2 = 0; c2 < 4; ++c2) {
                float2 fv = __half22float2(hp[c2]);
                int k = k8 + c2 * 2;
                As[k + 0][m ^ ((k + 0) & 28)] = fv.x;
                As[k + 1][m ^ ((k + 1) & 28)] = fv.y;
            }
        }
        #pragma unroll
        for (int r = 0; r < 2; ++r) {
            int f = tid + r * 256;
            int kb = f >> 4, n4 = (f & 15) << 2;
            float4 v = pz[r];
            v.x *= sc0; v.y *= sc0; v.z *= sc0; v.w *= sc0;
            *(float4*)&Bs[kb][n4] = v;
        }
        uint4 ny[2]; float4 nz[2];
        if (kt < 15) load_tiles(kt + 1, ny, nz);
        __syncthreads();
        #pragma unroll
        for (int kk = 0; kk < 32; ++kk) {
            const int sw = kk & 28;
            float a[8], b[4];
            *(float4*)(a)     = *(float4*)&As[kk][(ty * 4) ^ sw];
            *(float4*)(a + 4) = *(float4*)&As[kk][(64 + ty * 4) ^ sw];
            *(float4*)(b)     = *(float4*)&Bs[kk][tx * 4];
            #pragma unroll
            for (int i = 0; i < 8; ++i)
                #pragma unroll
                for (int jj = 0; jj < 4; ++jj)
                    acc[i][jj] += a[i] * b[jj];
        }
        __syncthreads();
        if (kt < 15) {
            py[0] = ny[0]; py[1] = ny[1]; pz[0] = nz[0]; pz[1] = nz[1];
        }
    }
    const float4 b4 = *(const float4*)(b_out + tx * 4);
    #pragma unroll
    for (int i = 0; i < 8; ++i) {
        int row = (i < 4) ? (ty * 4 + i) : (64 + ty * 4 + (i - 4));
        int m = m0 + row;
        if (m < N_NODES) {
            float4 r = *(float4*)&acc[i][0];
            r.x += b4.x; r.y += b4.y; r.z += b4.z; r.w += b4.w;
            *(float4*)(out + (size_t)m * OUT_CH + tx * 4) = r;
        }
    }
}

// ---------------------------------------------------------------------------
// Launch
// ---------------------------------------------------------------------------
extern "C" void kernel_launch(void* const* d_in, const int* in_sizes, int n_in,
                              void* d_out, int out_size, void* d_ws, size_t ws_size,
                              hipStream_t stream) {
    const float* x     = (const float*)d_in[0];
    const int*   ei    = (const int*)d_in[1];   // [2, E] int32
    const float* ew    = (const float*)d_in[2];
    const float* Wq    = (const float*)d_in[3];
    const float* Wk    = (const float*)d_in[4];
    const float* Wv    = (const float*)d_in[5];
    const float* We    = (const float*)d_in[6];
    const float* Wout  = (const float*)d_in[7];
    const float* b_out = (const float*)d_in[8];
    float* out = (float*)d_out;

    // workspace layout (~120 MB)
    __half* u16  = (__half*)d_ws;                          // 50000*512*2 = 51.2 MB
    __half* y16  = u16 + (size_t)N_NODES * UDIM;           // 51.2 MB
    __half* x16  = y16 + (size_t)N_NODES * UDIM;           // 50000*128*2 = 12.8 MB
    double* S    = (double*)(x16 + (size_t)N_NODES * IN_CH);  // 4 doubles (8B aligned)
    float*  M    = (float*)(S + HEADS);                    // 128*512
    float*  Zc   = M + IN_CH * UDIM;                       // 512*64
    int*    rp   = (int*)(Zc + UDIM * OUT_CH);             // 50000
    int*    cnt  = rp + N_NODES;                           // 50000
    int*    csum = cnt + N_NODES;                          // 64
    int2*   payload = (int2*)(csum + 64);                  // 500000*8 = 4 MB

    init_kernel<<<(N_NODES + 255) / 256, 256, 0, stream>>>(cnt, S);
    x16_kernel<<<(N_NODES * IN_CH / 4 + 255) / 256, 256, 0, stream>>>(x, x16);
    mbuild_kernel<<<HEADS, 256, 0, stream>>>(Wq, Wk, M);
    zbuild_kernel<<<HEADS, 256, 0, stream>>>(Wv, Wout, Zc);
    gemm_u_kernel<<<dim3((N_NODES + 127) / 128, 4), 256, 0, stream>>>(x, M, u16);
    hist_kernel<<<(N_EDGES + 255) / 256, 256, 0, stream>>>(ei, cnt);
    scan_reduce_kernel<<<NC, 256, 0, stream>>>(cnt, csum);
    scan_top_kernel<<<1, 64, 0, stream>>>(csum);
    scan_chunks_kernel<<<NC, 256, 0, stream>>>(cnt, csum, rp);
    scatter_kernel<<<(N_EDGES + 255) / 256, 256, 0, stream>>>(ei, ew, cnt, payload);
    edge_fused_kernel<<<N_NODES / 16, 256, 0, stream>>>(u16, x16, rp, cnt, payload, We, y16, S);
    gemm_out_kernel<<<(N_NODES + 127) / 128, 256, 0, stream>>>(y16, Zc, S, b_out, out);
}

// Round 7
// 499.505 us; speedup vs baseline: 13.5318x; 13.5318x over previous
//
#include <hip/hip_runtime.h>
#include <hip/hip_bf16.h>
#include <hip/hip_fp16.h>

// Problem constants
#define N_NODES 50000
#define N_EDGES 500000
#define IN_CH   128
#define D       256   // HEADS * OUT_CH
#define UDIM    512   // HEADS * 128 (u and y width)
#define OUT_CH  64
#define HEADS   4
#define NC      49    // scan chunks of 1024: ceil(50000/1024)

typedef _Float16 half8 __attribute__((ext_vector_type(8)));   // 4 VGPRs (MFMA A/B)
typedef float   floatx4 __attribute__((ext_vector_type(4)));  // 4 VGPRs (MFMA C/D)

// ---------------------------------------------------------------------------
// init: zero histogram counters and softmax denominators
// ---------------------------------------------------------------------------
__global__ __launch_bounds__(256) void init_kernel(int* __restrict__ cnt,
                                                   double* __restrict__ S) {
    int i = blockIdx.x * 256 + threadIdx.x;
    if (i < N_NODES) cnt[i] = 0;
    if (i < HEADS) S[i] = 0.0;
}

// ---------------------------------------------------------------------------
// x16 = fp16 copy of x (GEMM1 A-operand + edge-gather payload, 256 B/row)
// ---------------------------------------------------------------------------
__global__ __launch_bounds__(256) void x16_kernel(const float* __restrict__ x,
                                                  __half* __restrict__ x16) {
    int i = (blockIdx.x * 256 + threadIdx.x) * 4;
    if (i < N_NODES * IN_CH) {
        float4 v = *(const float4*)(x + i);
        union { __half2 h[2]; uint2 u; } pk;
        pk.h[0] = __floats2half2_rn(v.x, v.y);
        pk.h[1] = __floats2half2_rn(v.z, v.w);
        *(uint2*)(x16 + i) = pk.u;
    }
}

// ---------------------------------------------------------------------------
// M16t[(h*128+j)][i] = fp16( sum_c Wq[i][h*64+c] * Wk[j][h*64+c] )
// Transposed [512 x 128] fp16 so GEMM1 B-fragments are contiguous in k.
// ---------------------------------------------------------------------------
__global__ __launch_bounds__(256) void mbuild_kernel(const float* __restrict__ Wq,
                                                     const float* __restrict__ Wk,
                                                     __half* __restrict__ M16t) {
    const int h = blockIdx.x;
    const int tid = threadIdx.x;
    __shared__ float ks[128][64];
    for (int i = tid; i < 128 * 64; i += 256) {
        int r = i >> 6, c = i & 63;
        ks[r][c] = Wk[(size_t)r * D + h * 64 + c];
    }
    __syncthreads();
    const int i = tid >> 1;            // Wq row 0..127
    const int j0 = (tid & 1) * 64;     // col half
    float q[64];
    #pragma unroll 16
    for (int c = 0; c < 64; ++c) q[c] = Wq[(size_t)i * D + h * 64 + c];
    for (int jj = 0; jj < 64; ++jj) {
        int j = j0 + jj;
        float s = 0.f;
        #pragma unroll 16
        for (int c = 0; c < 64; ++c) s += q[c] * ks[j][c];
        M16t[(size_t)(h * 128 + j) * IN_CH + i] = __float2half(s);
    }
}

// ---------------------------------------------------------------------------
// Zc[(h*128+i)*64 + c] = sum_j Wv[i][h*64+j] * Wout[(h*64+j)][c]   (fp32)
// ---------------------------------------------------------------------------
__global__ __launch_bounds__(256) void zbuild_kernel(const float* __restrict__ Wv,
                                                     const float* __restrict__ Wout,
                                                     float* __restrict__ Zc) {
    int h = blockIdx.x;
    int tid = threadIdx.x;
    __shared__ float wo[64 * 64];
    for (int i = tid; i < 64 * 64; i += 256) {
        int j = i >> 6, c = i & 63;
        wo[i] = Wout[(h * 64 + j) * OUT_CH + c];
    }
    __syncthreads();
    int c = tid & 63, i0 = tid >> 6;
    for (int i = i0; i < IN_CH; i += 4) {
        float s = 0.f;
        const float* wv = Wv + (size_t)i * D + h * 64;
        #pragma unroll 8
        for (int j = 0; j < 64; ++j) s += wv[j] * wo[j * 64 + c];
        Zc[(size_t)(h * 128 + i) * OUT_CH + c] = s;
    }
}

// ---------------------------------------------------------------------------
// GEMM1 (MFMA): u16[50000x512] = x16 @ M16t^T, fp16 in / fp32 acc / fp16 out.
// Block = 128x128 tile, 4 waves. mfma_f32_16x16x32_f16.
// A-frag: a[j] = A[m0 + (lane&15)][k0 + (lane>>4)*8 + j]   (HW-verified layout)
// B-frag: b[j] = M16t[n0 + (lane&15)][k0 + (lane>>4)*8 + j]
// C/D:    elem(row = (lane>>4)*4 + reg, col = lane&15)
// Each thread stages one 64-half half-row = 8 x uint4 (128 B).
// ---------------------------------------------------------------------------
__global__ __launch_bounds__(256) void gemm_u_mfma_kernel(const __half* __restrict__ x16,
                                                          const __half* __restrict__ M16t,
                                                          __half* __restrict__ u16) {
    __shared__ __half Ax[128][136];
    __shared__ __half Bm[128][136];
    const int m0 = blockIdx.x * 128;
    const int colbase = blockIdx.y * 128;   // 0..3
    const int tid = threadIdx.x;

    // stage both tiles: thread -> (row = tid>>1, part = tid&1), 64 halves each
    {
        const int r = tid >> 1, part = tid & 1;
        uint4 va[8];
        if (m0 + r < N_NODES) {
            const uint4* src = (const uint4*)(x16 + (size_t)(m0 + r) * IN_CH + part * 64);
            #pragma unroll
            for (int q = 0; q < 8; ++q) va[q] = src[q];
        } else {
            #pragma unroll
            for (int q = 0; q < 8; ++q) va[q] = make_uint4(0u, 0u, 0u, 0u);
        }
        uint4* da = (uint4*)&Ax[r][part * 64];
        #pragma unroll
        for (int q = 0; q < 8; ++q) da[q] = va[q];
        const uint4* sb = (const uint4*)(M16t + (size_t)(colbase + r) * IN_CH + part * 64);
        uint4* db = (uint4*)&Bm[r][part * 64];
        #pragma unroll
        for (int q = 0; q < 8; ++q) db[q] = sb[q];
    }
    __syncthreads();

    const int w = tid >> 6, lane = tid & 63;
    const int mrow = lane & 15, quad = lane >> 4;

    // preload A-fragments: wave w owns rows [w*32, w*32+32) -> 2 m-tiles
    half8 a[2][4];
    #pragma unroll
    for (int mt = 0; mt < 2; ++mt)
        #pragma unroll
        for (int ks = 0; ks < 4; ++ks)
            a[mt][ks] = *(const half8*)&Ax[w * 32 + mt * 16 + mrow][ks * 32 + quad * 8];

    floatx4 acc[2][8];
    #pragma unroll
    for (int mt = 0; mt < 2; ++mt)
        #pragma unroll
        for (int nt = 0; nt < 8; ++nt)
            acc[mt][nt] = (floatx4){0.f, 0.f, 0.f, 0.f};

    #pragma unroll
    for (int nt = 0; nt < 8; ++nt) {
        #pragma unroll
        for (int ks = 0; ks < 4; ++ks) {
            half8 b = *(const half8*)&Bm[nt * 16 + mrow][ks * 32 + quad * 8];
            acc[0][nt] = __builtin_amdgcn_mfma_f32_16x16x32_f16(a[0][ks], b, acc[0][nt], 0, 0, 0);
            acc[1][nt] = __builtin_amdgcn_mfma_f32_16x16x32_f16(a[1][ks], b, acc[1][nt], 0, 0, 0);
        }
    }
    __syncthreads();
    // transpose C through LDS (reuse Ax) for vectorized global stores
    #pragma unroll
    for (int mt = 0; mt < 2; ++mt)
        #pragma unroll
        for (int nt = 0; nt < 8; ++nt)
            #pragma unroll
            for (int r = 0; r < 4; ++r)
                Ax[w * 32 + mt * 16 + quad * 4 + r][nt * 16 + mrow] = __float2half(acc[mt][nt][r]);
    __syncthreads();
    {
        const int r = tid >> 1, part = tid & 1;
        if (m0 + r < N_NODES) {
            const uint4* s4 = (const uint4*)&Ax[r][part * 64];
            uint4* d4 = (uint4*)(u16 + (size_t)(m0 + r) * UDIM + colbase + part * 64);
            #pragma unroll
            for (int q = 0; q < 8; ++q) d4[q] = s4[q];
        }
    }
}

// ---------------------------------------------------------------------------
// counting sort by tgt: histogram -> 3-phase scan -> scatter payload {src,w}
// ---------------------------------------------------------------------------
__global__ __launch_bounds__(256) void hist_kernel(const int* __restrict__ ei,
                                                   int* __restrict__ cnt) {
    int e = blockIdx.x * 256 + threadIdx.x;
    if (e < N_EDGES) atomicAdd(&cnt[ei[N_EDGES + e]], 1);
}

__global__ __launch_bounds__(256) void scan_reduce_kernel(const int* __restrict__ cnt,
                                                          int* __restrict__ csum) {
    const int b = blockIdx.x, tid = threadIdx.x;
    const int lane = tid & 63, wid = tid >> 6;
    int s = 0;
    int idx0 = b * 1024 + tid * 4;
    #pragma unroll
    for (int i = 0; i < 4; ++i) {
        int idx = idx0 + i;
        if (idx < N_NODES) s += cnt[idx];
    }
    #pragma unroll
    for (int m = 1; m < 64; m <<= 1) s += __shfl_xor(s, m, 64);
    __shared__ int w[4];
    if (lane == 0) w[wid] = s;
    __syncthreads();
    if (tid == 0) csum[b] = w[0] + w[1] + w[2] + w[3];
}

__global__ __launch_bounds__(64) void scan_top_kernel(int* __restrict__ csum) {
    int lane = threadIdx.x;
    int v = (lane < NC) ? csum[lane] : 0;
    int x = v;
    #pragma unroll
    for (int d = 1; d < 64; d <<= 1) {
        int y = __shfl_up(x, d, 64);
        if (lane >= d) x += y;
    }
    if (lane < NC) csum[lane] = x - v;   // exclusive
}

__global__ __launch_bounds__(256) void scan_chunks_kernel(int* __restrict__ cnt,
                                                          const int* __restrict__ csum,
                                                          int* __restrict__ rp) {
    const int b = blockIdx.x, tid = threadIdx.x;
    const int lane = tid & 63, wid = tid >> 6;
    __shared__ int wsum[4];
    int v[4];
    const int idx0 = b * 1024 + tid * 4;
    #pragma unroll
    for (int i = 0; i < 4; ++i) {
        int idx = idx0 + i;
        v[i] = (idx < N_NODES) ? cnt[idx] : 0;
    }
    int tsum = v[0] + v[1] + v[2] + v[3];
    int x = tsum;
    #pragma unroll
    for (int d = 1; d < 64; d <<= 1) {
        int y = __shfl_up(x, d, 64);
        if (lane >= d) x += y;
    }
    if (lane == 63) wsum[wid] = x;
    __syncthreads();
    int woff = 0;
    for (int w = 0; w < wid; ++w) woff += wsum[w];
    int excl = csum[b] + woff + x - tsum;
    #pragma unroll
    for (int i = 0; i < 4; ++i) {
        int idx = idx0 + i;
        if (idx < N_NODES) { rp[idx] = excl; cnt[idx] = excl; }
        excl += v[i];
    }
}

__global__ __launch_bounds__(256) void scatter_kernel(const int* __restrict__ ei,
                                                      const float* __restrict__ ew,
                                                      int* __restrict__ cnt,
                                                      int2* __restrict__ payload) {
    int e = blockIdx.x * 256 + threadIdx.x;
    if (e >= N_EDGES) return;
    int s = ei[e], t = ei[N_EDGES + e];
    int pos = atomicAdd(&cnt[t], 1);
    payload[pos] = make_int2(s, __float_as_int(ew[e]));
}

// ---------------------------------------------------------------------------
// Fused edge kernel: per tgt node (16 lanes), loop incoming edges:
//   gather x16_s (256 B), d_h = u_t . x_s (shfl-16), p = exp(leaky(...)),
//   y_h += p_h * x_s (fp32 regs) -> y16. Accumulate S[h] (double).
// ---------------------------------------------------------------------------
__global__ __launch_bounds__(256) void edge_fused_kernel(const __half* __restrict__ u16,
                                                         const __half* __restrict__ x16,
                                                         const int* __restrict__ rp,
                                                         const int* __restrict__ cnt,
                                                         const int2* __restrict__ payload,
                                                         const float* __restrict__ We,
                                                         __half* __restrict__ y16,
                                                         double* __restrict__ S) {
    const int tid = threadIdx.x;
    const int j = tid & 15;
    const int node = blockIdx.x * 16 + (tid >> 4);
    const float4 we = *(const float4*)We;
    const float wev[4] = {we.x, we.y, we.z, we.w};

    // u[node] fragment: lane j holds, per head h, halves [h*128 + j*8 .. +7]
    const __half* ur = u16 + (size_t)node * UDIM;
    float4 ua[4], ub[4], ya[4], yb[4];
    #pragma unroll
    for (int h = 0; h < 4; ++h) {
        uint4 raw = *(const uint4*)(ur + h * 128 + j * 8);
        const __half2* hp = (const __half2*)&raw;
        float2 f0 = __half22float2(hp[0]), f1 = __half22float2(hp[1]);
        float2 f2 = __half22float2(hp[2]), f3 = __half22float2(hp[3]);
        ua[h] = make_float4(f0.x, f0.y, f1.x, f1.y);
        ub[h] = make_float4(f2.x, f2.y, f3.x, f3.y);
        ya[h] = make_float4(0.f, 0.f, 0.f, 0.f);
        yb[h] = make_float4(0.f, 0.f, 0.f, 0.f);
    }

    float sacc[4] = {0.f, 0.f, 0.f, 0.f};
    const int start = rp[node];
    const int end = cnt[node];
    int2 pl = (start < end) ? payload[start] : make_int2(0, 0);
    for (int e = start; e < end; ++e) {
        int2 plnext = (e + 1 < end) ? payload[e + 1] : pl;   // software pipeline
        const int s = pl.x;
        const float w = __int_as_float(pl.y);
        uint4 raw = *(const uint4*)(x16 + (size_t)s * IN_CH + j * 8);
        const __half2* hp = (const __half2*)&raw;
        float2 f0 = __half22float2(hp[0]), f1 = __half22float2(hp[1]);
        float2 f2 = __half22float2(hp[2]), f3 = __half22float2(hp[3]);
        float4 xa = make_float4(f0.x, f0.y, f1.x, f1.y);
        float4 xb = make_float4(f2.x, f2.y, f3.x, f3.y);
        float d[4];
        #pragma unroll
        for (int h = 0; h < 4; ++h) {
            d[h] = ua[h].x * xa.x + ua[h].y * xa.y + ua[h].z * xa.z + ua[h].w * xa.w
                 + ub[h].x * xb.x + ub[h].y * xb.y + ub[h].z * xb.z + ub[h].w * xb.w;
        }
        #pragma unroll
        for (int m = 1; m < 16; m <<= 1) {
            #pragma unroll
            for (int h = 0; h < 4; ++h) d[h] += __shfl_xor(d[h], m, 16);
        }
        float p[4];
        #pragma unroll
        for (int h = 0; h < 4; ++h) {
            float l = d[h] * 0.125f + w * wev[h];
            l = (l > 0.f) ? l : 0.2f * l;
            p[h] = __expf(l);
        }
        #pragma unroll
        for (int h = 0; h < 4; ++h) {
            ya[h].x += p[h] * xa.x; ya[h].y += p[h] * xa.y;
            ya[h].z += p[h] * xa.z; ya[h].w += p[h] * xa.w;
            yb[h].x += p[h] * xb.x; yb[h].y += p[h] * xb.y;
            yb[h].z += p[h] * xb.z; yb[h].w += p[h] * xb.w;
        }
        if (j == 0) {
            sacc[0] += p[0]; sacc[1] += p[1]; sacc[2] += p[2]; sacc[3] += p[3];
        }
        pl = plnext;
    }
    // write y16 fragment
    __half* yr = y16 + (size_t)node * UDIM;
    #pragma unroll
    for (int h = 0; h < 4; ++h) {
        union { __half2 hh[4]; uint4 u; } pk;
        pk.hh[0] = __floats2half2_rn(ya[h].x, ya[h].y);
        pk.hh[1] = __floats2half2_rn(ya[h].z, ya[h].w);
        pk.hh[2] = __floats2half2_rn(yb[h].x, yb[h].y);
        pk.hh[3] = __floats2half2_rn(yb[h].z, yb[h].w);
        *(uint4*)(yr + h * 128 + j * 8) = pk.u;
    }
    __shared__ float sblk[4];
    if (tid < 4) sblk[tid] = 0.f;
    __syncthreads();
    if (j == 0) {
        atomicAdd(&sblk[0], sacc[0]);
        atomicAdd(&sblk[1], sacc[1]);
        atomicAdd(&sblk[2], sacc[2]);
        atomicAdd(&sblk[3], sacc[3]);
    }
    __syncthreads();
    if (tid < 4) atomicAdd(&S[tid], (double)sblk[tid]);
}

// ---------------------------------------------------------------------------
// GEMM2: out = (y16 scaled by 1/S per head) @ Zc[512,64] + b_out
// BM=128, BN=64, BK=32, 8x4 microtile, register prefetch (small: no spill),
// swizzled As.
// ---------------------------------------------------------------------------
__global__ __launch_bounds__(256) void gemm_out_kernel(const __half* __restrict__ y16,
                                                       const float* __restrict__ Zc,
                                                       const double* __restrict__ S,
                                                       const float* __restrict__ b_out,
                                                       float* __restrict__ out) {
    __shared__ float As[32][128];
    __shared__ float Bs[32][64];
    __shared__ float invs[4];

    const int m0 = blockIdx.x * 128;
    const int tid = threadIdx.x;
    const int tx = tid & 15, ty = tid >> 4;

    if (tid < 4) invs[tid] = (float)(1.0 / S[tid]);
    __syncthreads();

    float acc[8][4];
    #pragma unroll
    for (int i = 0; i < 8; ++i)
        #pragma unroll
        for (int jj = 0; jj < 4; ++jj) acc[i][jj] = 0.f;

    auto load_tiles = [&](int kt, uint4* py, float4* pz) {
        const int k0 = kt * 32;
        #pragma unroll
        for (int r = 0; r < 2; ++r) {
            int f = tid + r * 256;
            int m = f >> 2, k8 = (f & 3) << 3;
            py[r] = make_uint4(0u, 0u, 0u, 0u);
            if (m0 + m < N_NODES)
                py[r] = *(const uint4*)(y16 + (size_t)(m0 + m) * UDIM + k0 + k8);
        }
        #pragma unroll
        for (int r = 0; r < 2; ++r) {
            int f = tid + r * 256;
            int kb = f >> 4, n4 = (f & 15) << 2;
            pz[r] = *(const float4*)(Zc + (size_t)(k0 + kb) * OUT_CH + n4);
        }
    };

    uint4 py[2]; float4 pz[2];
    load_tiles(0, py, pz);

    for (int kt = 0; kt < 16; ++kt) {
        const float sc0 = invs[kt >> 2];   // 32-k tile within one head (128k/head)
        #pragma unroll
        for (int r = 0; r < 2; ++r) {
            int f = tid + r * 256;
            int m = f >> 2, k8 = (f & 3) << 3;
            const __half2* hp = (const __half2*)&py[r];
            #pragma unroll
            for (int c2 = 0; c2 < 4; ++c2) {
                float2 fv = __half22float2(hp[c2]);
                int k = k8 + c2 * 2;
                As[k + 0][m ^ ((k + 0) & 28)] = fv.x;
                As[k + 1][m ^ ((k + 1) & 28)] = fv.y;
            }
        }
        #pragma unroll
        for (int r = 0; r < 2; ++r) {
            int f = tid + r * 256;
            int kb = f >> 4, n4 = (f & 15) << 2;
            float4 v = pz[r];
            v.x *= sc0; v.y *= sc0; v.z *= sc0; v.w *= sc0;
            *(float4*)&Bs[kb][n4] = v;
        }
        uint4 ny[2]; float4 nz[2];
        if (kt < 15) load_tiles(kt + 1, ny, nz);
        __syncthreads();
        #pragma unroll
        for (int kk = 0; kk < 32; ++kk) {
            const int sw = kk & 28;
            float a[8], b[4];
            *(float4*)(a)     = *(float4*)&As[kk][(ty * 4) ^ sw];
            *(float4*)(a + 4) = *(float4*)&As[kk][(64 + ty * 4) ^ sw];
            *(float4*)(b)     = *(float4*)&Bs[kk][tx * 4];
            #pragma unroll
            for (int i = 0; i < 8; ++i)
                #pragma unroll
                for (int jj = 0; jj < 4; ++jj)
                    acc[i][jj] += a[i] * b[jj];
        }
        __syncthreads();
        if (kt < 15) {
            py[0] = ny[0]; py[1] = ny[1]; pz[0] = nz[0]; pz[1] = nz[1];
        }
    }
    const float4 b4 = *(const float4*)(b_out + tx * 4);
    #pragma unroll
    for (int i = 0; i < 8; ++i) {
        int row = (i < 4) ? (ty * 4 + i) : (64 + ty * 4 + (i - 4));
        int m = m0 + row;
        if (m < N_NODES) {
            float4 r = *(float4*)&acc[i][0];
            r.x += b4.x; r.y += b4.y; r.z += b4.z; r.w += b4.w;
            *(float4*)(out + (size_t)m * OUT_CH + tx * 4) = r;
        }
    }
}

// ---------------------------------------------------------------------------
// Launch
// ---------------------------------------------------------------------------
extern "C" void kernel_launch(void* const* d_in, const int* in_sizes, int n_in,
                              void* d_out, int out_size, void* d_ws, size_t ws_size,
                              hipStream_t stream) {
    const float* x     = (const float*)d_in[0];
    const int*   ei    = (const int*)d_in[1];   // [2, E] int32
    const float* ew    = (const float*)d_in[2];
    const float* Wq    = (const float*)d_in[3];
    const float* Wk    = (const float*)d_in[4];
    const float* Wv    = (const float*)d_in[5];
    const float* We    = (const float*)d_in[6];
    const float* Wout  = (const float*)d_in[7];
    const float* b_out = (const float*)d_in[8];
    float* out = (float*)d_out;

    // workspace layout (~120 MB)
    __half* u16  = (__half*)d_ws;                          // 50000*512*2 = 51.2 MB
    __half* y16  = u16 + (size_t)N_NODES * UDIM;           // 51.2 MB
    __half* x16  = y16 + (size_t)N_NODES * UDIM;           // 50000*128*2 = 12.8 MB
    double* S    = (double*)(x16 + (size_t)N_NODES * IN_CH);  // 4 doubles
    __half* M16t = (__half*)(S + HEADS);                   // 512*128*2 = 128 KB (16B-aligned)
    float*  Zc   = (float*)(M16t + UDIM * IN_CH);          // 512*64*4 = 128 KB
    int*    rp   = (int*)(Zc + UDIM * OUT_CH);             // 50000
    int*    cnt  = rp + N_NODES;                           // 50000
    int*    csum = cnt + N_NODES;                          // 64
    int2*   payload = (int2*)(csum + 64);                  // 500000*8 = 4 MB

    init_kernel<<<(N_NODES + 255) / 256, 256, 0, stream>>>(cnt, S);
    x16_kernel<<<(N_NODES * IN_CH / 4 + 255) / 256, 256, 0, stream>>>(x, x16);
    mbuild_kernel<<<HEADS, 256, 0, stream>>>(Wq, Wk, M16t);
    zbuild_kernel<<<HEADS, 256, 0, stream>>>(Wv, Wout, Zc);
    gemm_u_mfma_kernel<<<dim3((N_NODES + 127) / 128, 4), 256, 0, stream>>>(x16, M16t, u16);
    hist_kernel<<<(N_EDGES + 255) / 256, 256, 0, stream>>>(ei, cnt);
    scan_reduce_kernel<<<NC, 256, 0, stream>>>(cnt, csum);
    scan_top_kernel<<<1, 64, 0, stream>>>(csum);
    scan_chunks_kernel<<<NC, 256, 0, stream>>>(cnt, csum, rp);
    scatter_kernel<<<(N_EDGES + 255) / 256, 256, 0, stream>>>(ei, ew, cnt, payload);
    edge_fused_kernel<<<N_NODES / 16, 256, 0, stream>>>(u16, x16, rp, cnt, payload, We, y16, S);
    gemm_out_kernel<<<(N_NODES + 127) / 128, 256, 0, stream>>>(y16, Zc, S, b_out, out);
}

// Round 8
// 352.845 us; speedup vs baseline: 19.1563x; 1.4157x over previous
//
#include <hip/hip_runtime.h>
#include <hip/hip_bf16.h>
#include <hip/hip_fp16.h>

// Problem constants
#define N_NODES 50000
#define N_EDGES 500000
#define IN_CH   128
#define D       256   // HEADS * OUT_CH
#define UDIM    512   // HEADS * 128 (u and y width)
#define OUT_CH  64
#define HEADS   4
#define NC      49    // scan chunks of 1024: ceil(50000/1024)

typedef _Float16 half8 __attribute__((ext_vector_type(8)));   // 4 VGPRs (MFMA A/B)
typedef float   floatx4 __attribute__((ext_vector_type(4)));  // 4 VGPRs (MFMA C/D)

// ---------------------------------------------------------------------------
// init: zero histogram counters and softmax denominators
// ---------------------------------------------------------------------------
__global__ __launch_bounds__(256) void init_kernel(int* __restrict__ cnt,
                                                   double* __restrict__ S) {
    int i = blockIdx.x * 256 + threadIdx.x;
    if (i < N_NODES) cnt[i] = 0;
    if (i < HEADS) S[i] = 0.0;
}

// ---------------------------------------------------------------------------
// x16 = fp16 copy of x (GEMM1 A-operand + edge-gather payload, 256 B/row)
// ---------------------------------------------------------------------------
__global__ __launch_bounds__(256) void x16_kernel(const float* __restrict__ x,
                                                  __half* __restrict__ x16) {
    int i = (blockIdx.x * 256 + threadIdx.x) * 4;
    if (i < N_NODES * IN_CH) {
        float4 v = *(const float4*)(x + i);
        union { __half2 h[2]; uint2 u; } pk;
        pk.h[0] = __floats2half2_rn(v.x, v.y);
        pk.h[1] = __floats2half2_rn(v.z, v.w);
        *(uint2*)(x16 + i) = pk.u;
    }
}

// ---------------------------------------------------------------------------
// M16t[(h*128+j)][i] = fp16( sum_c Wq[i][h*64+c] * Wk[j][h*64+c] )
// One block per output row (512 blocks, 128 threads): Wk row in LDS
// (broadcast reads), Wq head-slice L1/L2-resident, coalesced row writes.
// ---------------------------------------------------------------------------
__global__ __launch_bounds__(128) void mbuild_kernel(const float* __restrict__ Wq,
                                                     const float* __restrict__ Wk,
                                                     __half* __restrict__ M16t) {
    const int r = blockIdx.x;          // 0..511 = h*128 + j
    const int h = r >> 7, j = r & 127;
    const int i = threadIdx.x;         // 0..127
    __shared__ float kj[64];
    if (i < 64) kj[i] = Wk[(size_t)j * D + h * 64 + i];
    __syncthreads();
    const float4* qr = (const float4*)(Wq + (size_t)i * D + h * 64);
    float s = 0.f;
    #pragma unroll
    for (int c4 = 0; c4 < 16; ++c4) {
        float4 q = qr[c4];
        s += q.x * kj[c4 * 4] + q.y * kj[c4 * 4 + 1]
           + q.z * kj[c4 * 4 + 2] + q.w * kj[c4 * 4 + 3];
    }
    M16t[(size_t)r * IN_CH + i] = __float2half(s);
}

// ---------------------------------------------------------------------------
// Zc[(h*128+i)*64 + c] = sum_j Wv[i][h*64+j] * Wout[(h*64+j)][c]   (fp32)
// One block per output row (512 blocks, 64 threads): Wv row in LDS
// (broadcast), Wout reads coalesced across c, coalesced row writes.
// ---------------------------------------------------------------------------
__global__ __launch_bounds__(64) void zbuild_kernel(const float* __restrict__ Wv,
                                                    const float* __restrict__ Wout,
                                                    float* __restrict__ Zc) {
    const int r = blockIdx.x;          // 0..511 = h*128 + i
    const int h = r >> 7, i = r & 127;
    const int c = threadIdx.x;         // 0..63
    __shared__ float vi[64];
    vi[c] = Wv[(size_t)i * D + h * 64 + c];
    __syncthreads();
    float s = 0.f;
    #pragma unroll 8
    for (int j = 0; j < 64; ++j)
        s += vi[j] * Wout[(size_t)(h * 64 + j) * OUT_CH + c];
    Zc[(size_t)r * OUT_CH + c] = s;
}

// ---------------------------------------------------------------------------
// GEMM1 (MFMA): u16[50000x512] = x16 @ M16t^T, fp16 in / fp32 acc / fp16 out.
// Block = 128x128 tile, 4 waves. mfma_f32_16x16x32_f16.
// A-frag: a[j] = A[m0 + (lane&15)][k0 + (lane>>4)*8 + j]   (HW-verified layout)
// B-frag: b[j] = M16t[n0 + (lane&15)][k0 + (lane>>4)*8 + j]
// C/D:    elem(row = (lane>>4)*4 + reg, col = lane&15)
// Each thread stages one 64-half half-row = 8 x uint4 (128 B).
// ---------------------------------------------------------------------------
__global__ __launch_bounds__(256) void gemm_u_mfma_kernel(const __half* __restrict__ x16,
                                                          const __half* __restrict__ M16t,
                                                          __half* __restrict__ u16) {
    __shared__ __half Ax[128][136];
    __shared__ __half Bm[128][136];
    const int m0 = blockIdx.x * 128;
    const int colbase = blockIdx.y * 128;   // 0..3
    const int tid = threadIdx.x;

    // stage both tiles: thread -> (row = tid>>1, part = tid&1), 64 halves each
    {
        const int r = tid >> 1, part = tid & 1;
        uint4 va[8];
        if (m0 + r < N_NODES) {
            const uint4* src = (const uint4*)(x16 + (size_t)(m0 + r) * IN_CH + part * 64);
            #pragma unroll
            for (int q = 0; q < 8; ++q) va[q] = src[q];
        } else {
            #pragma unroll
            for (int q = 0; q < 8; ++q) va[q] = make_uint4(0u, 0u, 0u, 0u);
        }
        uint4* da = (uint4*)&Ax[r][part * 64];
        #pragma unroll
        for (int q = 0; q < 8; ++q) da[q] = va[q];
        const uint4* sb = (const uint4*)(M16t + (size_t)(colbase + r) * IN_CH + part * 64);
        uint4* db = (uint4*)&Bm[r][part * 64];
        #pragma unroll
        for (int q = 0; q < 8; ++q) db[q] = sb[q];
    }
    __syncthreads();

    const int w = tid >> 6, lane = tid & 63;
    const int mrow = lane & 15, quad = lane >> 4;

    // preload A-fragments: wave w owns rows [w*32, w*32+32) -> 2 m-tiles
    half8 a[2][4];
    #pragma unroll
    for (int mt = 0; mt < 2; ++mt)
        #pragma unroll
        for (int ks = 0; ks < 4; ++ks)
            a[mt][ks] = *(const half8*)&Ax[w * 32 + mt * 16 + mrow][ks * 32 + quad * 8];

    floatx4 acc[2][8];
    #pragma unroll
    for (int mt = 0; mt < 2; ++mt)
        #pragma unroll
        for (int nt = 0; nt < 8; ++nt)
            acc[mt][nt] = (floatx4){0.f, 0.f, 0.f, 0.f};

    #pragma unroll
    for (int nt = 0; nt < 8; ++nt) {
        #pragma unroll
        for (int ks = 0; ks < 4; ++ks) {
            half8 b = *(const half8*)&Bm[nt * 16 + mrow][ks * 32 + quad * 8];
            acc[0][nt] = __builtin_amdgcn_mfma_f32_16x16x32_f16(a[0][ks], b, acc[0][nt], 0, 0, 0);
            acc[1][nt] = __builtin_amdgcn_mfma_f32_16x16x32_f16(a[1][ks], b, acc[1][nt], 0, 0, 0);
        }
    }
    __syncthreads();
    // transpose C through LDS (reuse Ax) for vectorized global stores
    #pragma unroll
    for (int mt = 0; mt < 2; ++mt)
        #pragma unroll
        for (int nt = 0; nt < 8; ++nt)
            #pragma unroll
            for (int r = 0; r < 4; ++r)
                Ax[w * 32 + mt * 16 + quad * 4 + r][nt * 16 + mrow] = __float2half(acc[mt][nt][r]);
    __syncthreads();
    {
        const int r = tid >> 1, part = tid & 1;
        if (m0 + r < N_NODES) {
            const uint4* s4 = (const uint4*)&Ax[r][part * 64];
            uint4* d4 = (uint4*)(u16 + (size_t)(m0 + r) * UDIM + colbase + part * 64);
            #pragma unroll
            for (int q = 0; q < 8; ++q) d4[q] = s4[q];
        }
    }
}

// ---------------------------------------------------------------------------
// counting sort by tgt: histogram -> 3-phase scan -> scatter payload {src,w}
// ---------------------------------------------------------------------------
__global__ __launch_bounds__(256) void hist_kernel(const int* __restrict__ ei,
                                                   int* __restrict__ cnt) {
    int e = blockIdx.x * 256 + threadIdx.x;
    if (e < N_EDGES) atomicAdd(&cnt[ei[N_EDGES + e]], 1);
}

__global__ __launch_bounds__(256) void scan_reduce_kernel(const int* __restrict__ cnt,
                                                          int* __restrict__ csum) {
    const int b = blockIdx.x, tid = threadIdx.x;
    const int lane = tid & 63, wid = tid >> 6;
    int s = 0;
    int idx0 = b * 1024 + tid * 4;
    #pragma unroll
    for (int i = 0; i < 4; ++i) {
        int idx = idx0 + i;
        if (idx < N_NODES) s += cnt[idx];
    }
    #pragma unroll
    for (int m = 1; m < 64; m <<= 1) s += __shfl_xor(s, m, 64);
    __shared__ int w[4];
    if (lane == 0) w[wid] = s;
    __syncthreads();
    if (tid == 0) csum[b] = w[0] + w[1] + w[2] + w[3];
}

__global__ __launch_bounds__(64) void scan_top_kernel(int* __restrict__ csum) {
    int lane = threadIdx.x;
    int v = (lane < NC) ? csum[lane] : 0;
    int x = v;
    #pragma unroll
    for (int d = 1; d < 64; d <<= 1) {
        int y = __shfl_up(x, d, 64);
        if (lane >= d) x += y;
    }
    if (lane < NC) csum[lane] = x - v;   // exclusive
}

__global__ __launch_bounds__(256) void scan_chunks_kernel(int* __restrict__ cnt,
                                                          const int* __restrict__ csum,
                                                          int* __restrict__ rp) {
    const int b = blockIdx.x, tid = threadIdx.x;
    const int lane = tid & 63, wid = tid >> 6;
    __shared__ int wsum[4];
    int v[4];
    const int idx0 = b * 1024 + tid * 4;
    #pragma unroll
    for (int i = 0; i < 4; ++i) {
        int idx = idx0 + i;
        v[i] = (idx < N_NODES) ? cnt[idx] : 0;
    }
    int tsum = v[0] + v[1] + v[2] + v[3];
    int x = tsum;
    #pragma unroll
    for (int d = 1; d < 64; d <<= 1) {
        int y = __shfl_up(x, d, 64);
        if (lane >= d) x += y;
    }
    if (lane == 63) wsum[wid] = x;
    __syncthreads();
    int woff = 0;
    for (int w = 0; w < wid; ++w) woff += wsum[w];
    int excl = csum[b] + woff + x - tsum;
    #pragma unroll
    for (int i = 0; i < 4; ++i) {
        int idx = idx0 + i;
        if (idx < N_NODES) { rp[idx] = excl; cnt[idx] = excl; }
        excl += v[i];
    }
}

__global__ __launch_bounds__(256) void scatter_kernel(const int* __restrict__ ei,
                                                      const float* __restrict__ ew,
                                                      int* __restrict__ cnt,
                                                      int2* __restrict__ payload) {
    int e = blockIdx.x * 256 + threadIdx.x;
    if (e >= N_EDGES) return;
    int s = ei[e], t = ei[N_EDGES + e];
    int pos = atomicAdd(&cnt[t], 1);
    payload[pos] = make_int2(s, __float_as_int(ew[e]));
}

// ---------------------------------------------------------------------------
// Fused edge kernel: per tgt node (16 lanes), loop incoming edges:
//   gather x16_s (256 B), d_h = u_t . x_s (shfl-16), p = exp(leaky(...)),
//   y_h += p_h * x_s (fp32 regs) -> y16. Accumulate S[h] (double).
// ---------------------------------------------------------------------------
__global__ __launch_bounds__(256) void edge_fused_kernel(const __half* __restrict__ u16,
                                                         const __half* __restrict__ x16,
                                                         const int* __restrict__ rp,
                                                         const int* __restrict__ cnt,
                                                         const int2* __restrict__ payload,
                                                         const float* __restrict__ We,
                                                         __half* __restrict__ y16,
                                                         double* __restrict__ S) {
    const int tid = threadIdx.x;
    const int j = tid & 15;
    const int node = blockIdx.x * 16 + (tid >> 4);
    const float4 we = *(const float4*)We;
    const float wev[4] = {we.x, we.y, we.z, we.w};

    // u[node] fragment: lane j holds, per head h, halves [h*128 + j*8 .. +7]
    const __half* ur = u16 + (size_t)node * UDIM;
    float4 ua[4], ub[4], ya[4], yb[4];
    #pragma unroll
    for (int h = 0; h < 4; ++h) {
        uint4 raw = *(const uint4*)(ur + h * 128 + j * 8);
        const __half2* hp = (const __half2*)&raw;
        float2 f0 = __half22float2(hp[0]), f1 = __half22float2(hp[1]);
        float2 f2 = __half22float2(hp[2]), f3 = __half22float2(hp[3]);
        ua[h] = make_float4(f0.x, f0.y, f1.x, f1.y);
        ub[h] = make_float4(f2.x, f2.y, f3.x, f3.y);
        ya[h] = make_float4(0.f, 0.f, 0.f, 0.f);
        yb[h] = make_float4(0.f, 0.f, 0.f, 0.f);
    }

    float sacc[4] = {0.f, 0.f, 0.f, 0.f};
    const int start = rp[node];
    const int end = cnt[node];
    int2 pl = (start < end) ? payload[start] : make_int2(0, 0);
    for (int e = start; e < end; ++e) {
        int2 plnext = (e + 1 < end) ? payload[e + 1] : pl;   // software pipeline
        const int s = pl.x;
        const float w = __int_as_float(pl.y);
        uint4 raw = *(const uint4*)(x16 + (size_t)s * IN_CH + j * 8);
        const __half2* hp = (const __half2*)&raw;
        float2 f0 = __half22float2(hp[0]), f1 = __half22float2(hp[1]);
        float2 f2 = __half22float2(hp[2]), f3 = __half22float2(hp[3]);
        float4 xa = make_float4(f0.x, f0.y, f1.x, f1.y);
        float4 xb = make_float4(f2.x, f2.y, f3.x, f3.y);
        float d[4];
        #pragma unroll
        for (int h = 0; h < 4; ++h) {
            d[h] = ua[h].x * xa.x + ua[h].y * xa.y + ua[h].z * xa.z + ua[h].w * xa.w
                 + ub[h].x * xb.x + ub[h].y * xb.y + ub[h].z * xb.z + ub[h].w * xb.w;
        }
        #pragma unroll
        for (int m = 1; m < 16; m <<= 1) {
            #pragma unroll
            for (int h = 0; h < 4; ++h) d[h] += __shfl_xor(d[h], m, 16);
        }
        float p[4];
        #pragma unroll
        for (int h = 0; h < 4; ++h) {
            float l = d[h] * 0.125f + w * wev[h];
            l = (l > 0.f) ? l : 0.2f * l;
            p[h] = __expf(l);
        }
        #pragma unroll
        for (int h = 0; h < 4; ++h) {
            ya[h].x += p[h] * xa.x; ya[h].y += p[h] * xa.y;
            ya[h].z += p[h] * xa.z; ya[h].w += p[h] * xa.w;
            yb[h].x += p[h] * xb.x; yb[h].y += p[h] * xb.y;
            yb[h].z += p[h] * xb.z; yb[h].w += p[h] * xb.w;
        }
        if (j == 0) {
            sacc[0] += p[0]; sacc[1] += p[1]; sacc[2] += p[2]; sacc[3] += p[3];
        }
        pl = plnext;
    }
    // write y16 fragment
    __half* yr = y16 + (size_t)node * UDIM;
    #pragma unroll
    for (int h = 0; h < 4; ++h) {
        union { __half2 hh[4]; uint4 u; } pk;
        pk.hh[0] = __floats2half2_rn(ya[h].x, ya[h].y);
        pk.hh[1] = __floats2half2_rn(ya[h].z, ya[h].w);
        pk.hh[2] = __floats2half2_rn(yb[h].x, yb[h].y);
        pk.hh[3] = __floats2half2_rn(yb[h].z, yb[h].w);
        *(uint4*)(yr + h * 128 + j * 8) = pk.u;
    }
    __shared__ float sblk[4];
    if (tid < 4) sblk[tid] = 0.f;
    __syncthreads();
    if (j == 0) {
        atomicAdd(&sblk[0], sacc[0]);
        atomicAdd(&sblk[1], sacc[1]);
        atomicAdd(&sblk[2], sacc[2]);
        atomicAdd(&sblk[3], sacc[3]);
    }
    __syncthreads();
    if (tid < 4) atomicAdd(&S[tid], (double)sblk[tid]);
}

// ---------------------------------------------------------------------------
// GEMM2: out = (y16 scaled by 1/S per head) @ Zc[512,64] + b_out
// BM=128, BN=64, BK=32, 8x4 microtile, register prefetch (small: no spill),
// swizzled As.
// ---------------------------------------------------------------------------
__global__ __launch_bounds__(256) void gemm_out_kernel(const __half* __restrict__ y16,
                                                       const float* __restrict__ Zc,
                                                       const double* __restrict__ S,
                                                       const float* __restrict__ b_out,
                                                       float* __restrict__ out) {
    __shared__ float As[32][128];
    __shared__ float Bs[32][64];
    __shared__ float invs[4];

    const int m0 = blockIdx.x * 128;
    const int tid = threadIdx.x;
    const int tx = tid & 15, ty = tid >> 4;

    if (tid < 4) invs[tid] = (float)(1.0 / S[tid]);
    __syncthreads();

    float acc[8][4];
    #pragma unroll
    for (int i = 0; i < 8; ++i)
        #pragma unroll
        for (int jj = 0; jj < 4; ++jj) acc[i][jj] = 0.f;

    auto load_tiles = [&](int kt, uint4* py, float4* pz) {
        const int k0 = kt * 32;
        #pragma unroll
        for (int r = 0; r < 2; ++r) {
            int f = tid + r * 256;
            int m = f >> 2, k8 = (f & 3) << 3;
            py[r] = make_uint4(0u, 0u, 0u, 0u);
            if (m0 + m < N_NODES)
                py[r] = *(const uint4*)(y16 + (size_t)(m0 + m) * UDIM + k0 + k8);
        }
        #pragma unroll
        for (int r = 0; r < 2; ++r) {
            int f = tid + r * 256;
            int kb = f >> 4, n4 = (f & 15) << 2;
            pz[r] = *(const float4*)(Zc + (size_t)(k0 + kb) * OUT_CH + n4);
        }
    };

    uint4 py[2]; float4 pz[2];
    load_tiles(0, py, pz);

    for (int kt = 0; kt < 16; ++kt) {
        const float sc0 = invs[kt >> 2];   // 32-k tile within one head (128k/head)
        #pragma unroll
        for (int r = 0; r < 2; ++r) {
            int f = tid + r * 256;
            int m = f >> 2, k8 = (f & 3) << 3;
            const __half2* hp = (const __half2*)&py[r];
            #pragma unroll
            for (int c2 = 0; c2 < 4; ++c2) {
                float2 fv = __half22float2(hp[c2]);
                int k = k8 + c2 * 2;
                As[k + 0][m ^ ((k + 0) & 28)] = fv.x;
                As[k + 1][m ^ ((k + 1) & 28)] = fv.y;
            }
        }
        #pragma unroll
        for (int r = 0; r < 2; ++r) {
            int f = tid + r * 256;
            int kb = f >> 4, n4 = (f & 15) << 2;
            float4 v = pz[r];
            v.x *= sc0; v.y *= sc0; v.z *= sc0; v.w *= sc0;
            *(float4*)&Bs[kb][n4] = v;
        }
        uint4 ny[2]; float4 nz[2];
        if (kt < 15) load_tiles(kt + 1, ny, nz);
        __syncthreads();
        #pragma unroll
        for (int kk = 0; kk < 32; ++kk) {
            const int sw = kk & 28;
            float a[8], b[4];
            *(float4*)(a)     = *(float4*)&As[kk][(ty * 4) ^ sw];
            *(float4*)(a + 4) = *(float4*)&As[kk][(64 + ty * 4) ^ sw];
            *(float4*)(b)     = *(float4*)&Bs[kk][tx * 4];
            #pragma unroll
            for (int i = 0; i < 8; ++i)
                #pragma unroll
                for (int jj = 0; jj < 4; ++jj)
                    acc[i][jj] += a[i] * b[jj];
        }
        __syncthreads();
        if (kt < 15) {
            py[0] = ny[0]; py[1] = ny[1]; pz[0] = nz[0]; pz[1] = nz[1];
        }
    }
    const float4 b4 = *(const float4*)(b_out + tx * 4);
    #pragma unroll
    for (int i = 0; i < 8; ++i) {
        int row = (i < 4) ? (ty * 4 + i) : (64 + ty * 4 + (i - 4));
        int m = m0 + row;
        if (m < N_NODES) {
            float4 r = *(float4*)&acc[i][0];
            r.x += b4.x; r.y += b4.y; r.z += b4.z; r.w += b4.w;
            *(float4*)(out + (size_t)m * OUT_CH + tx * 4) = r;
        }
    }
}

// ---------------------------------------------------------------------------
// Launch
// ---------------------------------------------------------------------------
extern "C" void kernel_launch(void* const* d_in, const int* in_sizes, int n_in,
                              void* d_out, int out_size, void* d_ws, size_t ws_size,
                              hipStream_t stream) {
    const float* x     = (const float*)d_in[0];
    const int*   ei    = (const int*)d_in[1];   // [2, E] int32
    const float* ew    = (const float*)d_in[2];
    const float* Wq    = (const float*)d_in[3];
    const float* Wk    = (const float*)d_in[4];
    const float* Wv    = (const float*)d_in[5];
    const float* We    = (const float*)d_in[6];
    const float* Wout  = (const float*)d_in[7];
    const float* b_out = (const float*)d_in[8];
    float* out = (float*)d_out;

    // workspace layout (~120 MB)
    __half* u16  = (__half*)d_ws;                          // 50000*512*2 = 51.2 MB
    __half* y16  = u16 + (size_t)N_NODES * UDIM;           // 51.2 MB
    __half* x16  = y16 + (size_t)N_NODES * UDIM;           // 50000*128*2 = 12.8 MB
    double* S    = (double*)(x16 + (size_t)N_NODES * IN_CH);  // 4 doubles
    __half* M16t = (__half*)(S + HEADS);                   // 512*128*2 = 128 KB (16B-aligned)
    float*  Zc   = (float*)(M16t + UDIM * IN_CH);          // 512*64*4 = 128 KB
    int*    rp   = (int*)(Zc + UDIM * OUT_CH);             // 50000
    int*    cnt  = rp + N_NODES;                           // 50000
    int*    csum = cnt + N_NODES;                          // 64
    int2*   payload = (int2*)(csum + 64);                  // 500000*8 = 4 MB

    init_kernel<<<(N_NODES + 255) / 256, 256, 0, stream>>>(cnt, S);
    x16_kernel<<<(N_NODES * IN_CH / 4 + 255) / 256, 256, 0, stream>>>(x, x16);
    mbuild_kernel<<<512, 128, 0, stream>>>(Wq, Wk, M16t);
    zbuild_kernel<<<512, 64, 0, stream>>>(Wv, Wout, Zc);
    gemm_u_mfma_kernel<<<dim3((N_NODES + 127) / 128, 4), 256, 0, stream>>>(x16, M16t, u16);
    hist_kernel<<<(N_EDGES + 255) / 256, 256, 0, stream>>>(ei, cnt);
    scan_reduce_kernel<<<NC, 256, 0, stream>>>(cnt, csum);
    scan_top_kernel<<<1, 64, 0, stream>>>(csum);
    scan_chunks_kernel<<<NC, 256, 0, stream>>>(cnt, csum, rp);
    scatter_kernel<<<(N_EDGES + 255) / 256, 256, 0, stream>>>(ei, ew, cnt, payload);
    edge_fused_kernel<<<N_NODES / 16, 256, 0, stream>>>(u16, x16, rp, cnt, payload, We, y16, S);
    gemm_out_kernel<<<(N_NODES + 127) / 128, 256, 0, stream>>>(y16, Zc, S, b_out, out);
}

// Round 10
// 282.153 us; speedup vs baseline: 23.9557x; 1.2505x over previous
//
#include <hip/hip_runtime.h>
#include <hip/hip_bf16.h>
#include <hip/hip_fp16.h>

// Problem constants
#define N_NODES 50000
#define N_EDGES 500000
#define IN_CH   128
#define D       256   // HEADS * OUT_CH
#define UDIM    512   // HEADS * 128 (u and y width)
#define OUT_CH  64
#define HEADS   4
#define NC      49    // scan chunks of 1024: ceil(50000/1024)

typedef _Float16 half8 __attribute__((ext_vector_type(8)));   // 4 VGPRs (MFMA A/B)
typedef float   floatx4 __attribute__((ext_vector_type(4)));  // 4 VGPRs (MFMA C/D)

// ---------------------------------------------------------------------------
// init: zero histogram counters and softmax denominators
// ---------------------------------------------------------------------------
__global__ __launch_bounds__(256) void init_kernel(int* __restrict__ cnt,
                                                   double* __restrict__ S) {
    int i = blockIdx.x * 256 + threadIdx.x;
    if (i < N_NODES) cnt[i] = 0;
    if (i < HEADS) S[i] = 0.0;
}

// ---------------------------------------------------------------------------
// x16 = fp16 copy of x (GEMM1 A-operand + edge-gather payload, 256 B/row)
// ---------------------------------------------------------------------------
__global__ __launch_bounds__(256) void x16_kernel(const float* __restrict__ x,
                                                  __half* __restrict__ x16) {
    int i = (blockIdx.x * 256 + threadIdx.x) * 4;
    if (i < N_NODES * IN_CH) {
        float4 v = *(const float4*)(x + i);
        union { __half2 h[2]; uint2 u; } pk;
        pk.h[0] = __floats2half2_rn(v.x, v.y);
        pk.h[1] = __floats2half2_rn(v.z, v.w);
        *(uint2*)(x16 + i) = pk.u;
    }
}

// ---------------------------------------------------------------------------
// M16t[(h*128+j)][i] = fp16( sum_c Wq[i][h*64+c] * Wk[j][h*64+c] )
// One block per output row (512 blocks, 128 threads).
// ---------------------------------------------------------------------------
__global__ __launch_bounds__(128) void mbuild_kernel(const float* __restrict__ Wq,
                                                     const float* __restrict__ Wk,
                                                     __half* __restrict__ M16t) {
    const int r = blockIdx.x;          // 0..511 = h*128 + j
    const int h = r >> 7, j = r & 127;
    const int i = threadIdx.x;         // 0..127
    __shared__ float kj[64];
    if (i < 64) kj[i] = Wk[(size_t)j * D + h * 64 + i];
    __syncthreads();
    const float4* qr = (const float4*)(Wq + (size_t)i * D + h * 64);
    float s = 0.f;
    #pragma unroll
    for (int c4 = 0; c4 < 16; ++c4) {
        float4 q = qr[c4];
        s += q.x * kj[c4 * 4] + q.y * kj[c4 * 4 + 1]
           + q.z * kj[c4 * 4 + 2] + q.w * kj[c4 * 4 + 3];
    }
    M16t[(size_t)r * IN_CH + i] = __float2half(s);
}

// ---------------------------------------------------------------------------
// Zc16t[c][h*128+i] = fp16( sum_j Wv[i][h*64+j] * Wout[(h*64+j)][c] )
// Transposed [64 x 512] fp16: MFMA B-operand layout for gemm_out (k-contig).
// ---------------------------------------------------------------------------
__global__ __launch_bounds__(64) void zbuild_kernel(const float* __restrict__ Wv,
                                                    const float* __restrict__ Wout,
                                                    __half* __restrict__ Zc16t) {
    const int r = blockIdx.x;          // 0..511 = h*128 + i
    const int h = r >> 7, i = r & 127;
    const int c = threadIdx.x;         // 0..63
    __shared__ float vi[64];
    vi[c] = Wv[(size_t)i * D + h * 64 + c];
    __syncthreads();
    float s = 0.f;
    #pragma unroll 8
    for (int j = 0; j < 64; ++j)
        s += vi[j] * Wout[(size_t)(h * 64 + j) * OUT_CH + c];
    Zc16t[(size_t)c * UDIM + r] = __float2half(s);
}

// ---------------------------------------------------------------------------
// GEMM1 (MFMA): u16[50000x512] = x16 @ M16t^T, fp16 in / fp32 acc / fp16 out.
// Block = 128x128 tile, 4 waves. mfma_f32_16x16x32_f16.
// ---------------------------------------------------------------------------
__global__ __launch_bounds__(256) void gemm_u_mfma_kernel(const __half* __restrict__ x16,
                                                          const __half* __restrict__ M16t,
                                                          __half* __restrict__ u16) {
    __shared__ __half Ax[128][136];
    __shared__ __half Bm[128][136];
    const int m0 = blockIdx.x * 128;
    const int colbase = blockIdx.y * 128;   // 0..3
    const int tid = threadIdx.x;

    {
        const int r = tid >> 1, part = tid & 1;   // 64 halves = 8 uint4 per thread
        uint4 va[8];
        if (m0 + r < N_NODES) {
            const uint4* src = (const uint4*)(x16 + (size_t)(m0 + r) * IN_CH + part * 64);
            #pragma unroll
            for (int q = 0; q < 8; ++q) va[q] = src[q];
        } else {
            #pragma unroll
            for (int q = 0; q < 8; ++q) va[q] = make_uint4(0u, 0u, 0u, 0u);
        }
        uint4* da = (uint4*)&Ax[r][part * 64];
        #pragma unroll
        for (int q = 0; q < 8; ++q) da[q] = va[q];
        const uint4* sb = (const uint4*)(M16t + (size_t)(colbase + r) * IN_CH + part * 64);
        uint4* db = (uint4*)&Bm[r][part * 64];
        #pragma unroll
        for (int q = 0; q < 8; ++q) db[q] = sb[q];
    }
    __syncthreads();

    const int w = tid >> 6, lane = tid & 63;
    const int mrow = lane & 15, quad = lane >> 4;

    half8 a[2][4];
    #pragma unroll
    for (int mt = 0; mt < 2; ++mt)
        #pragma unroll
        for (int ks = 0; ks < 4; ++ks)
            a[mt][ks] = *(const half8*)&Ax[w * 32 + mt * 16 + mrow][ks * 32 + quad * 8];

    floatx4 acc[2][8];
    #pragma unroll
    for (int mt = 0; mt < 2; ++mt)
        #pragma unroll
        for (int nt = 0; nt < 8; ++nt)
            acc[mt][nt] = (floatx4){0.f, 0.f, 0.f, 0.f};

    #pragma unroll
    for (int nt = 0; nt < 8; ++nt) {
        #pragma unroll
        for (int ks = 0; ks < 4; ++ks) {
            half8 b = *(const half8*)&Bm[nt * 16 + mrow][ks * 32 + quad * 8];
            acc[0][nt] = __builtin_amdgcn_mfma_f32_16x16x32_f16(a[0][ks], b, acc[0][nt], 0, 0, 0);
            acc[1][nt] = __builtin_amdgcn_mfma_f32_16x16x32_f16(a[1][ks], b, acc[1][nt], 0, 0, 0);
        }
    }
    __syncthreads();
    #pragma unroll
    for (int mt = 0; mt < 2; ++mt)
        #pragma unroll
        for (int nt = 0; nt < 8; ++nt)
            #pragma unroll
            for (int r = 0; r < 4; ++r)
                Ax[w * 32 + mt * 16 + quad * 4 + r][nt * 16 + mrow] = __float2half(acc[mt][nt][r]);
    __syncthreads();
    {
        const int r = tid >> 1, part = tid & 1;
        if (m0 + r < N_NODES) {
            const uint4* s4 = (const uint4*)&Ax[r][part * 64];
            uint4* d4 = (uint4*)(u16 + (size_t)(m0 + r) * UDIM + colbase + part * 64);
            #pragma unroll
            for (int q = 0; q < 8; ++q) d4[q] = s4[q];
        }
    }
}

// ---------------------------------------------------------------------------
// counting sort by tgt: histogram -> 3-phase scan -> scatter payload {src,w}
// ---------------------------------------------------------------------------
__global__ __launch_bounds__(256) void hist_kernel(const int* __restrict__ ei,
                                                   int* __restrict__ cnt) {
    int e = blockIdx.x * 256 + threadIdx.x;
    if (e < N_EDGES) atomicAdd(&cnt[ei[N_EDGES + e]], 1);
}

__global__ __launch_bounds__(256) void scan_reduce_kernel(const int* __restrict__ cnt,
                                                          int* __restrict__ csum) {
    const int b = blockIdx.x, tid = threadIdx.x;
    const int lane = tid & 63, wid = tid >> 6;
    int s = 0;
    int idx0 = b * 1024 + tid * 4;
    #pragma unroll
    for (int i = 0; i < 4; ++i) {
        int idx = idx0 + i;
        if (idx < N_NODES) s += cnt[idx];
    }
    #pragma unroll
    for (int m = 1; m < 64; m <<= 1) s += __shfl_xor(s, m, 64);
    __shared__ int w[4];
    if (lane == 0) w[wid] = s;
    __syncthreads();
    if (tid == 0) csum[b] = w[0] + w[1] + w[2] + w[3];
}

__global__ __launch_bounds__(64) void scan_top_kernel(int* __restrict__ csum) {
    int lane = threadIdx.x;
    int v = (lane < NC) ? csum[lane] : 0;
    int x = v;
    #pragma unroll
    for (int d = 1; d < 64; d <<= 1) {
        int y = __shfl_up(x, d, 64);
        if (lane >= d) x += y;
    }
    if (lane < NC) csum[lane] = x - v;   // exclusive
}

__global__ __launch_bounds__(256) void scan_chunks_kernel(int* __restrict__ cnt,
                                                          const int* __restrict__ csum,
                                                          int* __restrict__ rp) {
    const int b = blockIdx.x, tid = threadIdx.x;
    const int lane = tid & 63, wid = tid >> 6;
    __shared__ int wsum[4];
    int v[4];
    const int idx0 = b * 1024 + tid * 4;
    #pragma unroll
    for (int i = 0; i < 4; ++i) {
        int idx = idx0 + i;
        v[i] = (idx < N_NODES) ? cnt[idx] : 0;
    }
    int tsum = v[0] + v[1] + v[2] + v[3];
    int x = tsum;
    #pragma unroll
    for (int d = 1; d < 64; d <<= 1) {
        int y = __shfl_up(x, d, 64);
        if (lane >= d) x += y;
    }
    if (lane == 63) wsum[wid] = x;
    __syncthreads();
    int woff = 0;
    for (int w = 0; w < wid; ++w) woff += wsum[w];
    int excl = csum[b] + woff + x - tsum;
    #pragma unroll
    for (int i = 0; i < 4; ++i) {
        int idx = idx0 + i;
        if (idx < N_NODES) { rp[idx] = excl; cnt[idx] = excl; }
        excl += v[i];
    }
}

__global__ __launch_bounds__(256) void scatter_kernel(const int* __restrict__ ei,
                                                      const float* __restrict__ ew,
                                                      int* __restrict__ cnt,
                                                      int2* __restrict__ payload) {
    int e = blockIdx.x * 256 + threadIdx.x;
    if (e >= N_EDGES) return;
    int s = ei[e], t = ei[N_EDGES + e];
    int pos = atomicAdd(&cnt[t], 1);
    payload[pos] = make_int2(s, __float_as_int(ew[e]));
}

// ---------------------------------------------------------------------------
// Fused edge kernel: per tgt node (16 lanes), loop incoming edges:
//   gather x16_s (256 B), d_h = u_t . x_s (shfl-16), p = exp(leaky(...)),
//   y_h += p_h * x_s (fp32 regs) -> y16. Accumulate S[h] (double).
// ---------------------------------------------------------------------------
__global__ __launch_bounds__(256) void edge_fused_kernel(const __half* __restrict__ u16,
                                                         const __half* __restrict__ x16,
                                                         const int* __restrict__ rp,
                                                         const int* __restrict__ cnt,
                                                         const int2* __restrict__ payload,
                                                         const float* __restrict__ We,
                                                         __half* __restrict__ y16,
                                                         double* __restrict__ S) {
    const int tid = threadIdx.x;
    const int j = tid & 15;
    const int node = blockIdx.x * 16 + (tid >> 4);
    const float4 we = *(const float4*)We;
    const float wev[4] = {we.x, we.y, we.z, we.w};

    const __half* ur = u16 + (size_t)node * UDIM;
    float4 ua[4], ub[4], ya[4], yb[4];
    #pragma unroll
    for (int h = 0; h < 4; ++h) {
        uint4 raw = *(const uint4*)(ur + h * 128 + j * 8);
        const __half2* hp = (const __half2*)&raw;
        float2 f0 = __half22float2(hp[0]), f1 = __half22float2(hp[1]);
        float2 f2 = __half22float2(hp[2]), f3 = __half22float2(hp[3]);
        ua[h] = make_float4(f0.x, f0.y, f1.x, f1.y);
        ub[h] = make_float4(f2.x, f2.y, f3.x, f3.y);
        ya[h] = make_float4(0.f, 0.f, 0.f, 0.f);
        yb[h] = make_float4(0.f, 0.f, 0.f, 0.f);
    }

    float sacc[4] = {0.f, 0.f, 0.f, 0.f};
    const int start = rp[node];
    const int end = cnt[node];
    int2 pl = (start < end) ? payload[start] : make_int2(0, 0);
    for (int e = start; e < end; ++e) {
        int2 plnext = (e + 1 < end) ? payload[e + 1] : pl;   // software pipeline
        const int s = pl.x;
        const float w = __int_as_float(pl.y);
        uint4 raw = *(const uint4*)(x16 + (size_t)s * IN_CH + j * 8);
        const __half2* hp = (const __half2*)&raw;
        float2 f0 = __half22float2(hp[0]), f1 = __half22float2(hp[1]);
        float2 f2 = __half22float2(hp[2]), f3 = __half22float2(hp[3]);
        float4 xa = make_float4(f0.x, f0.y, f1.x, f1.y);
        float4 xb = make_float4(f2.x, f2.y, f3.x, f3.y);
        float d[4];
        #pragma unroll
        for (int h = 0; h < 4; ++h) {
            d[h] = ua[h].x * xa.x + ua[h].y * xa.y + ua[h].z * xa.z + ua[h].w * xa.w
                 + ub[h].x * xb.x + ub[h].y * xb.y + ub[h].z * xb.z + ub[h].w * xb.w;
        }
        #pragma unroll
        for (int m = 1; m < 16; m <<= 1) {
            #pragma unroll
            for (int h = 0; h < 4; ++h) d[h] += __shfl_xor(d[h], m, 16);
        }
        float p[4];
        #pragma unroll
        for (int h = 0; h < 4; ++h) {
            float l = d[h] * 0.125f + w * wev[h];
            l = (l > 0.f) ? l : 0.2f * l;
            p[h] = __expf(l);
        }
        #pragma unroll
        for (int h = 0; h < 4; ++h) {
            ya[h].x += p[h] * xa.x; ya[h].y += p[h] * xa.y;
            ya[h].z += p[h] * xa.z; ya[h].w += p[h] * xa.w;
            yb[h].x += p[h] * xb.x; yb[h].y += p[h] * xb.y;
            yb[h].z += p[h] * xb.z; yb[h].w += p[h] * xb.w;
        }
        if (j == 0) {
            sacc[0] += p[0]; sacc[1] += p[1]; sacc[2] += p[2]; sacc[3] += p[3];
        }
        pl = plnext;
    }
    __half* yr = y16 + (size_t)node * UDIM;
    #pragma unroll
    for (int h = 0; h < 4; ++h) {
        union { __half2 hh[4]; uint4 u; } pk;
        pk.hh[0] = __floats2half2_rn(ya[h].x, ya[h].y);
        pk.hh[1] = __floats2half2_rn(ya[h].z, ya[h].w);
        pk.hh[2] = __floats2half2_rn(yb[h].x, yb[h].y);
        pk.hh[3] = __floats2half2_rn(yb[h].z, yb[h].w);
        *(uint4*)(yr + h * 128 + j * 8) = pk.u;
    }
    __shared__ float sblk[4];
    if (tid < 4) sblk[tid] = 0.f;
    __syncthreads();
    if (j == 0) {
        atomicAdd(&sblk[0], sacc[0]);
        atomicAdd(&sblk[1], sacc[1]);
        atomicAdd(&sblk[2], sacc[2]);
        atomicAdd(&sblk[3], sacc[3]);
    }
    __syncthreads();
    if (tid < 4) atomicAdd(&S[tid], (double)sblk[tid]);
}

// ---------------------------------------------------------------------------
// GEMM2 (MFMA): out[50000x64] = sum_h invs[h] * (y16_h @ Zc16t_h^T) + b_out.
// Block = 128 rows x 64 cols, 4 waves; per-head accumulate + epilogue fold.
// Staging invariant: threads x bytes/thread == tile bytes
//   A: 256 x 128 B = 32 KB (128x128 halves) -> 8 uint4/thread
//   B: 256 x  64 B = 16 KB ( 64x128 halves) -> 4 uint4/thread
// ---------------------------------------------------------------------------
__global__ __launch_bounds__(256) void gemm_out_mfma_kernel(const __half* __restrict__ y16,
                                                            const __half* __restrict__ Zc16t,
                                                            const double* __restrict__ S,
                                                            const float* __restrict__ b_out,
                                                            float* __restrict__ out) {
    __shared__ __half Ay[128][136];
    __shared__ __half Bz[64][136];
    __shared__ float invs_s[4];
    const int m0 = blockIdx.x * 128;
    const int tid = threadIdx.x;
    if (tid < 4) invs_s[tid] = (float)(1.0 / S[tid]);

    const int w = tid >> 6, lane = tid & 63;
    const int mrow = lane & 15, quad = lane >> 4;

    floatx4 result[2][4];
    #pragma unroll
    for (int mt = 0; mt < 2; ++mt)
        #pragma unroll
        for (int nt = 0; nt < 4; ++nt)
            result[mt][nt] = (floatx4){0.f, 0.f, 0.f, 0.f};

    for (int h = 0; h < HEADS; ++h) {
        // stage A: y16 rows [m0,m0+128), cols [h*128, h*128+128): 8 uint4/thread
        {
            const int r = tid >> 1, part = tid & 1;   // part covers 64 halves
            uint4 va[8];
            if (m0 + r < N_NODES) {
                const uint4* src = (const uint4*)(y16 + (size_t)(m0 + r) * UDIM + h * 128 + part * 64);
                #pragma unroll
                for (int q = 0; q < 8; ++q) va[q] = src[q];
            } else {
                #pragma unroll
                for (int q = 0; q < 8; ++q) va[q] = make_uint4(0u, 0u, 0u, 0u);
            }
            uint4* da = (uint4*)&Ay[r][part * 64];
            #pragma unroll
            for (int q = 0; q < 8; ++q) da[q] = va[q];
        }
        // stage B: Zc16t rows [0,64), cols [h*128, h*128+128): 4 uint4/thread
        {
            const int r = tid >> 2, part = tid & 3;   // part covers 32 halves
            const uint4* sb = (const uint4*)(Zc16t + (size_t)r * UDIM + h * 128 + part * 32);
            uint4* db = (uint4*)&Bz[r][part * 32];
            #pragma unroll
            for (int q = 0; q < 4; ++q) db[q] = sb[q];
        }
        __syncthreads();

        half8 a[2][4];
        #pragma unroll
        for (int mt = 0; mt < 2; ++mt)
            #pragma unroll
            for (int ks = 0; ks < 4; ++ks)
                a[mt][ks] = *(const half8*)&Ay[w * 32 + mt * 16 + mrow][ks * 32 + quad * 8];

        floatx4 acc[2][4];
        #pragma unroll
        for (int mt = 0; mt < 2; ++mt)
            #pragma unroll
            for (int nt = 0; nt < 4; ++nt)
                acc[mt][nt] = (floatx4){0.f, 0.f, 0.f, 0.f};

        #pragma unroll
        for (int nt = 0; nt < 4; ++nt) {
            #pragma unroll
            for (int ks = 0; ks < 4; ++ks) {
                half8 b = *(const half8*)&Bz[nt * 16 + mrow][ks * 32 + quad * 8];
                acc[0][nt] = __builtin_amdgcn_mfma_f32_16x16x32_f16(a[0][ks], b, acc[0][nt], 0, 0, 0);
                acc[1][nt] = __builtin_amdgcn_mfma_f32_16x16x32_f16(a[1][ks], b, acc[1][nt], 0, 0, 0);
            }
        }
        const float inv = invs_s[h];
        #pragma unroll
        for (int mt = 0; mt < 2; ++mt)
            #pragma unroll
            for (int nt = 0; nt < 4; ++nt) {
                result[mt][nt][0] += inv * acc[mt][nt][0];
                result[mt][nt][1] += inv * acc[mt][nt][1];
                result[mt][nt][2] += inv * acc[mt][nt][2];
                result[mt][nt][3] += inv * acc[mt][nt][3];
            }
        __syncthreads();
    }
    // epilogue: out[row][col] = result + b_out[col]
    float bcol[4];
    #pragma unroll
    for (int nt = 0; nt < 4; ++nt) bcol[nt] = b_out[nt * 16 + mrow];
    #pragma unroll
    for (int mt = 0; mt < 2; ++mt) {
        #pragma unroll
        for (int r = 0; r < 4; ++r) {
            int row = m0 + w * 32 + mt * 16 + quad * 4 + r;
            if (row < N_NODES) {
                float* dst = out + (size_t)row * OUT_CH;
                #pragma unroll
                for (int nt = 0; nt < 4; ++nt)
                    dst[nt * 16 + mrow] = result[mt][nt][r] + bcol[nt];
            }
        }
    }
}

// ---------------------------------------------------------------------------
// Launch
// ---------------------------------------------------------------------------
extern "C" void kernel_launch(void* const* d_in, const int* in_sizes, int n_in,
                              void* d_out, int out_size, void* d_ws, size_t ws_size,
                              hipStream_t stream) {
    const float* x     = (const float*)d_in[0];
    const int*   ei    = (const int*)d_in[1];   // [2, E] int32
    const float* ew    = (const float*)d_in[2];
    const float* Wq    = (const float*)d_in[3];
    const float* Wk    = (const float*)d_in[4];
    const float* Wv    = (const float*)d_in[5];
    const float* We    = (const float*)d_in[6];
    const float* Wout  = (const float*)d_in[7];
    const float* b_out = (const float*)d_in[8];
    float* out = (float*)d_out;

    // workspace layout (~120 MB)
    __half* u16   = (__half*)d_ws;                          // 50000*512*2 = 51.2 MB
    __half* y16   = u16 + (size_t)N_NODES * UDIM;           // 51.2 MB
    __half* x16   = y16 + (size_t)N_NODES * UDIM;           // 12.8 MB
    double* S     = (double*)(x16 + (size_t)N_NODES * IN_CH);  // 4 doubles
    __half* M16t  = (__half*)(S + HEADS);                   // 512*128*2 = 128 KB
    __half* Zc16t = M16t + UDIM * IN_CH;                    // 64*512*2 = 64 KB
    int*    rp    = (int*)(Zc16t + OUT_CH * UDIM);          // 50000
    int*    cnt   = rp + N_NODES;                           // 50000
    int*    csum  = cnt + N_NODES;                          // 64
    int2*   payload = (int2*)(csum + 64);                   // 500000*8 = 4 MB

    init_kernel<<<(N_NODES + 255) / 256, 256, 0, stream>>>(cnt, S);
    x16_kernel<<<(N_NODES * IN_CH / 4 + 255) / 256, 256, 0, stream>>>(x, x16);
    mbuild_kernel<<<512, 128, 0, stream>>>(Wq, Wk, M16t);
    zbuild_kernel<<<512, 64, 0, stream>>>(Wv, Wout, Zc16t);
    gemm_u_mfma_kernel<<<dim3((N_NODES + 127) / 128, 4), 256, 0, stream>>>(x16, M16t, u16);
    hist_kernel<<<(N_EDGES + 255) / 256, 256, 0, stream>>>(ei, cnt);
    scan_reduce_kernel<<<NC, 256, 0, stream>>>(cnt, csum);
    scan_top_kernel<<<1, 64, 0, stream>>>(csum);
    scan_chunks_kernel<<<NC, 256, 0, stream>>>(cnt, csum, rp);
    scatter_kernel<<<(N_EDGES + 255) / 256, 256, 0, stream>>>(ei, ew, cnt, payload);
    edge_fused_kernel<<<N_NODES / 16, 256, 0, stream>>>(u16, x16, rp, cnt, payload, We, y16, S);
    gemm_out_mfma_kernel<<<(N_NODES + 127) / 128, 256, 0, stream>>>(y16, Zc16t, S, b_out, out);
}

// Round 11
// 272.549 us; speedup vs baseline: 24.7999x; 1.0352x over previous
//
#include <hip/hip_runtime.h>
#include <hip/hip_bf16.h>
#include <hip/hip_fp16.h>

// Problem constants
#define N_NODES 50000
#define N_EDGES 500000
#define IN_CH   128
#define D       256   // HEADS * OUT_CH
#define UDIM    512   // HEADS * 128 (u and y width)
#define OUT_CH  64
#define HEADS   4
#define NC      49    // scan chunks of 1024: ceil(50000/1024)

typedef _Float16 half8 __attribute__((ext_vector_type(8)));   // 4 VGPRs (MFMA A/B)
typedef _Float16 half2_t __attribute__((ext_vector_type(2))); // 1 VGPR packed
typedef float   floatx4 __attribute__((ext_vector_type(4)));  // 4 VGPRs (MFMA C/D)

// ---------------------------------------------------------------------------
// prep: zero cnt + S, and convert x -> x16 (fp16), fused into one launch
// ---------------------------------------------------------------------------
__global__ __launch_bounds__(256) void prep_kernel(const float* __restrict__ x,
                                                   __half* __restrict__ x16,
                                                   int* __restrict__ cnt,
                                                   double* __restrict__ S) {
    int i = blockIdx.x * 256 + threadIdx.x;
    if (i < N_NODES) cnt[i] = 0;
    if (i < HEADS) S[i] = 0.0;
    int k = i * 4;
    if (k < N_NODES * IN_CH) {
        float4 v = *(const float4*)(x + k);
        union { __half2 h[2]; uint2 u; } pk;
        pk.h[0] = __floats2half2_rn(v.x, v.y);
        pk.h[1] = __floats2half2_rn(v.z, v.w);
        *(uint2*)(x16 + k) = pk.u;
    }
}

// ---------------------------------------------------------------------------
// wbuild: blocks 0..511   -> M16t[(h*128+j)][i] = fp16(sum_c Wq[i][hc] Wk[j][hc])
//         blocks 512..1023-> Zc16t[c][h*128+i]  = fp16(sum_j Wv[i][hj] Wout[hj][c])
// ---------------------------------------------------------------------------
__global__ __launch_bounds__(128) void wbuild_kernel(const float* __restrict__ Wq,
                                                     const float* __restrict__ Wk,
                                                     const float* __restrict__ Wv,
                                                     const float* __restrict__ Wout,
                                                     __half* __restrict__ M16t,
                                                     __half* __restrict__ Zc16t) {
    __shared__ float buf[64];
    const int tid = threadIdx.x;
    if (blockIdx.x < 512) {
        const int r = blockIdx.x;          // h*128 + j
        const int h = r >> 7, j = r & 127;
        if (tid < 64) buf[tid] = Wk[(size_t)j * D + h * 64 + tid];
        __syncthreads();
        const float4* qr = (const float4*)(Wq + (size_t)tid * D + h * 64);
        float s = 0.f;
        #pragma unroll
        for (int c4 = 0; c4 < 16; ++c4) {
            float4 q = qr[c4];
            s += q.x * buf[c4 * 4] + q.y * buf[c4 * 4 + 1]
               + q.z * buf[c4 * 4 + 2] + q.w * buf[c4 * 4 + 3];
        }
        M16t[(size_t)r * IN_CH + tid] = __float2half(s);
    } else {
        const int r = blockIdx.x - 512;    // h*128 + i
        const int h = r >> 7, i = r & 127;
        if (tid < 64) buf[tid] = Wv[(size_t)i * D + h * 64 + tid];
        __syncthreads();
        if (tid < 64) {
            float s = 0.f;
            #pragma unroll 8
            for (int j = 0; j < 64; ++j)
                s += buf[j] * Wout[(size_t)(h * 64 + j) * OUT_CH + tid];
            Zc16t[(size_t)tid * UDIM + r] = __float2half(s);
        }
    }
}

// ---------------------------------------------------------------------------
// GEMM1 (MFMA): u16[50000x512] = x16 @ M16t^T, fp16 in / fp32 acc / fp16 out.
// Block = 128x128 tile, 4 waves. mfma_f32_16x16x32_f16.
// ---------------------------------------------------------------------------
__global__ __launch_bounds__(256) void gemm_u_mfma_kernel(const __half* __restrict__ x16,
                                                          const __half* __restrict__ M16t,
                                                          __half* __restrict__ u16) {
    __shared__ __half Ax[128][136];
    __shared__ __half Bm[128][136];
    const int m0 = blockIdx.x * 128;
    const int colbase = blockIdx.y * 128;   // 0..3
    const int tid = threadIdx.x;

    {
        const int r = tid >> 1, part = tid & 1;   // 64 halves = 8 uint4 per thread
        uint4 va[8];
        if (m0 + r < N_NODES) {
            const uint4* src = (const uint4*)(x16 + (size_t)(m0 + r) * IN_CH + part * 64);
            #pragma unroll
            for (int q = 0; q < 8; ++q) va[q] = src[q];
        } else {
            #pragma unroll
            for (int q = 0; q < 8; ++q) va[q] = make_uint4(0u, 0u, 0u, 0u);
        }
        uint4* da = (uint4*)&Ax[r][part * 64];
        #pragma unroll
        for (int q = 0; q < 8; ++q) da[q] = va[q];
        const uint4* sb = (const uint4*)(M16t + (size_t)(colbase + r) * IN_CH + part * 64);
        uint4* db = (uint4*)&Bm[r][part * 64];
        #pragma unroll
        for (int q = 0; q < 8; ++q) db[q] = sb[q];
    }
    __syncthreads();

    const int w = tid >> 6, lane = tid & 63;
    const int mrow = lane & 15, quad = lane >> 4;

    half8 a[2][4];
    #pragma unroll
    for (int mt = 0; mt < 2; ++mt)
        #pragma unroll
        for (int ks = 0; ks < 4; ++ks)
            a[mt][ks] = *(const half8*)&Ax[w * 32 + mt * 16 + mrow][ks * 32 + quad * 8];

    floatx4 acc[2][8];
    #pragma unroll
    for (int mt = 0; mt < 2; ++mt)
        #pragma unroll
        for (int nt = 0; nt < 8; ++nt)
            acc[mt][nt] = (floatx4){0.f, 0.f, 0.f, 0.f};

    #pragma unroll
    for (int nt = 0; nt < 8; ++nt) {
        #pragma unroll
        for (int ks = 0; ks < 4; ++ks) {
            half8 b = *(const half8*)&Bm[nt * 16 + mrow][ks * 32 + quad * 8];
            acc[0][nt] = __builtin_amdgcn_mfma_f32_16x16x32_f16(a[0][ks], b, acc[0][nt], 0, 0, 0);
            acc[1][nt] = __builtin_amdgcn_mfma_f32_16x16x32_f16(a[1][ks], b, acc[1][nt], 0, 0, 0);
        }
    }
    __syncthreads();
    #pragma unroll
    for (int mt = 0; mt < 2; ++mt)
        #pragma unroll
        for (int nt = 0; nt < 8; ++nt)
            #pragma unroll
            for (int r = 0; r < 4; ++r)
                Ax[w * 32 + mt * 16 + quad * 4 + r][nt * 16 + mrow] = __float2half(acc[mt][nt][r]);
    __syncthreads();
    {
        const int r = tid >> 1, part = tid & 1;
        if (m0 + r < N_NODES) {
            const uint4* s4 = (const uint4*)&Ax[r][part * 64];
            uint4* d4 = (uint4*)(u16 + (size_t)(m0 + r) * UDIM + colbase + part * 64);
            #pragma unroll
            for (int q = 0; q < 8; ++q) d4[q] = s4[q];
        }
    }
}

// ---------------------------------------------------------------------------
// counting sort by tgt: histogram -> 3-phase scan -> scatter payload {src,w}
// ---------------------------------------------------------------------------
__global__ __launch_bounds__(256) void hist_kernel(const int* __restrict__ ei,
                                                   int* __restrict__ cnt) {
    int e = blockIdx.x * 256 + threadIdx.x;
    if (e < N_EDGES) atomicAdd(&cnt[ei[N_EDGES + e]], 1);
}

__global__ __launch_bounds__(256) void scan_reduce_kernel(const int* __restrict__ cnt,
                                                          int* __restrict__ csum) {
    const int b = blockIdx.x, tid = threadIdx.x;
    const int lane = tid & 63, wid = tid >> 6;
    int s = 0;
    int idx0 = b * 1024 + tid * 4;
    #pragma unroll
    for (int i = 0; i < 4; ++i) {
        int idx = idx0 + i;
        if (idx < N_NODES) s += cnt[idx];
    }
    #pragma unroll
    for (int m = 1; m < 64; m <<= 1) s += __shfl_xor(s, m, 64);
    __shared__ int w[4];
    if (lane == 0) w[wid] = s;
    __syncthreads();
    if (tid == 0) csum[b] = w[0] + w[1] + w[2] + w[3];
}

__global__ __launch_bounds__(64) void scan_top_kernel(int* __restrict__ csum) {
    int lane = threadIdx.x;
    int v = (lane < NC) ? csum[lane] : 0;
    int x = v;
    #pragma unroll
    for (int d = 1; d < 64; d <<= 1) {
        int y = __shfl_up(x, d, 64);
        if (lane >= d) x += y;
    }
    if (lane < NC) csum[lane] = x - v;   // exclusive
}

__global__ __launch_bounds__(256) void scan_chunks_kernel(int* __restrict__ cnt,
                                                          const int* __restrict__ csum,
                                                          int* __restrict__ rp) {
    const int b = blockIdx.x, tid = threadIdx.x;
    const int lane = tid & 63, wid = tid >> 6;
    __shared__ int wsum[4];
    int v[4];
    const int idx0 = b * 1024 + tid * 4;
    #pragma unroll
    for (int i = 0; i < 4; ++i) {
        int idx = idx0 + i;
        v[i] = (idx < N_NODES) ? cnt[idx] : 0;
    }
    int tsum = v[0] + v[1] + v[2] + v[3];
    int x = tsum;
    #pragma unroll
    for (int d = 1; d < 64; d <<= 1) {
        int y = __shfl_up(x, d, 64);
        if (lane >= d) x += y;
    }
    if (lane == 63) wsum[wid] = x;
    __syncthreads();
    int woff = 0;
    for (int w = 0; w < wid; ++w) woff += wsum[w];
    int excl = csum[b] + woff + x - tsum;
    #pragma unroll
    for (int i = 0; i < 4; ++i) {
        int idx = idx0 + i;
        if (idx < N_NODES) { rp[idx] = excl; cnt[idx] = excl; }
        excl += v[i];
    }
}

__global__ __launch_bounds__(256) void scatter_kernel(const int* __restrict__ ei,
                                                      const float* __restrict__ ew,
                                                      int* __restrict__ cnt,
                                                      int2* __restrict__ payload) {
    int e = blockIdx.x * 256 + threadIdx.x;
    if (e >= N_EDGES) return;
    int s = ei[e], t = ei[N_EDGES + e];
    int pos = atomicAdd(&cnt[t], 1);
    payload[pos] = make_int2(s, __float_as_int(ew[e]));
}

// ---------------------------------------------------------------------------
// Fused edge kernel v2 (head-striped lanes):
// 16 lanes/node; lane j = head (j>>2), channel-quarter (j&3)*32.
// Per edge: prefetched 64 B x16 slice, 16 x v_dot2_f32_f16 (fp32 acc),
// 2-shfl quarter reduction, 1 exp/lane, 16 x v_pk_fma_f16 y-accumulate.
// y stays packed fp16 in registers; one 64 B store per lane at the end.
// ---------------------------------------------------------------------------
__global__ __launch_bounds__(256) void edge_fused_kernel(const __half* __restrict__ u16,
                                                         const __half* __restrict__ x16,
                                                         const int* __restrict__ rp,
                                                         const int* __restrict__ cnt,
                                                         const int2* __restrict__ payload,
                                                         const float* __restrict__ We,
                                                         __half* __restrict__ y16,
                                                         double* __restrict__ S) {
    const int tid = threadIdx.x;
    const int l16 = tid & 15;
    const int h = l16 >> 2;          // head 0..3
    const int q = l16 & 3;           // channel quarter 0..3
    const int node = blockIdx.x * 16 + (tid >> 4);
    const float wev = We[h];

    // u fragment: 32 halves = u16[node][h*128 + q*32 .. +31]
    uint4 ur[4];
    {
        const uint4* ub = (const uint4*)(u16 + (size_t)node * UDIM + h * 128 + q * 32);
        ur[0] = ub[0]; ur[1] = ub[1]; ur[2] = ub[2]; ur[3] = ub[3];
    }
    const half2_t* uh = (const half2_t*)ur;    // 16 half2

    half2_t yacc[16];
    #pragma unroll
    for (int t = 0; t < 16; ++t) yacc[t] = (half2_t){(_Float16)0.f, (_Float16)0.f};

    float sacc = 0.f;
    const int start = rp[node];
    const int end = cnt[node];
    int2 pl = make_int2(0, 0);
    uint4 xr[4];
    if (start < end) {
        pl = payload[start];
        const uint4* xb = (const uint4*)(x16 + (size_t)pl.x * IN_CH + q * 32);
        xr[0] = xb[0]; xr[1] = xb[1]; xr[2] = xb[2]; xr[3] = xb[3];
    }
    for (int e = start; e < end; ++e) {
        // prefetch next edge's payload + x-slice (in flight during compute)
        int2 pln = pl;
        uint4 xrn[4] = {xr[0], xr[1], xr[2], xr[3]};
        if (e + 1 < end) {
            pln = payload[e + 1];
            const uint4* xb = (const uint4*)(x16 + (size_t)pln.x * IN_CH + q * 32);
            xrn[0] = xb[0]; xrn[1] = xb[1]; xrn[2] = xb[2]; xrn[3] = xb[3];
        }
        const half2_t* xh = (const half2_t*)xr;
        float dot = 0.f;
        #pragma unroll
        for (int t = 0; t < 16; ++t)
            dot = __builtin_amdgcn_fdot2(uh[t], xh[t], dot, false);
        dot += __shfl_xor(dot, 1, 16);
        dot += __shfl_xor(dot, 2, 16);
        float l = dot * 0.125f + __int_as_float(pl.y) * wev;
        l = fmaxf(l, 0.2f * l);          // leaky_relu(0.2)
        float p = __expf(l);
        if (q == 0) sacc += p;
        half2_t p2 = (half2_t){(_Float16)p, (_Float16)p};
        #pragma unroll
        for (int t = 0; t < 16; ++t)
            yacc[t] = p2 * xh[t] + yacc[t];   // v_pk_fma_f16
        pl = pln;
        xr[0] = xrn[0]; xr[1] = xrn[1]; xr[2] = xrn[2]; xr[3] = xrn[3];
    }
    // write y fragment (this lane's exclusive 32 channels)
    {
        uint4* yo = (uint4*)(y16 + (size_t)node * UDIM + h * 128 + q * 32);
        const uint4* ys = (const uint4*)yacc;
        yo[0] = ys[0]; yo[1] = ys[1]; yo[2] = ys[2]; yo[3] = ys[3];
    }
    __shared__ float sblk[4];
    if (tid < 4) sblk[tid] = 0.f;
    __syncthreads();
    if (q == 0) atomicAdd(&sblk[h], sacc);
    __syncthreads();
    if (tid < 4) atomicAdd(&S[tid], (double)sblk[tid]);
}

// ---------------------------------------------------------------------------
// GEMM2 (MFMA): out[50000x64] = sum_h invs[h] * (y16_h @ Zc16t_h^T) + b_out.
// Staging invariant: threads x bytes/thread == tile bytes
//   A: 256 x 128 B = 32 KB (128x128 halves) -> 8 uint4/thread
//   B: 256 x  64 B = 16 KB ( 64x128 halves) -> 4 uint4/thread
// ---------------------------------------------------------------------------
__global__ __launch_bounds__(256) void gemm_out_mfma_kernel(const __half* __restrict__ y16,
                                                            const __half* __restrict__ Zc16t,
                                                            const double* __restrict__ S,
                                                            const float* __restrict__ b_out,
                                                            float* __restrict__ out) {
    __shared__ __half Ay[128][136];
    __shared__ __half Bz[64][136];
    __shared__ float invs_s[4];
    const int m0 = blockIdx.x * 128;
    const int tid = threadIdx.x;
    if (tid < 4) invs_s[tid] = (float)(1.0 / S[tid]);

    const int w = tid >> 6, lane = tid & 63;
    const int mrow = lane & 15, quad = lane >> 4;

    floatx4 result[2][4];
    #pragma unroll
    for (int mt = 0; mt < 2; ++mt)
        #pragma unroll
        for (int nt = 0; nt < 4; ++nt)
            result[mt][nt] = (floatx4){0.f, 0.f, 0.f, 0.f};

    for (int h = 0; h < HEADS; ++h) {
        {
            const int r = tid >> 1, part = tid & 1;   // 8 uint4/thread
            uint4 va[8];
            if (m0 + r < N_NODES) {
                const uint4* src = (const uint4*)(y16 + (size_t)(m0 + r) * UDIM + h * 128 + part * 64);
                #pragma unroll
                for (int qq = 0; qq < 8; ++qq) va[qq] = src[qq];
            } else {
                #pragma unroll
                for (int qq = 0; qq < 8; ++qq) va[qq] = make_uint4(0u, 0u, 0u, 0u);
            }
            uint4* da = (uint4*)&Ay[r][part * 64];
            #pragma unroll
            for (int qq = 0; qq < 8; ++qq) da[qq] = va[qq];
        }
        {
            const int r = tid >> 2, part = tid & 3;   // 4 uint4/thread
            const uint4* sb = (const uint4*)(Zc16t + (size_t)r * UDIM + h * 128 + part * 32);
            uint4* db = (uint4*)&Bz[r][part * 32];
            #pragma unroll
            for (int qq = 0; qq < 4; ++qq) db[qq] = sb[qq];
        }
        __syncthreads();

        half8 a[2][4];
        #pragma unroll
        for (int mt = 0; mt < 2; ++mt)
            #pragma unroll
            for (int ks = 0; ks < 4; ++ks)
                a[mt][ks] = *(const half8*)&Ay[w * 32 + mt * 16 + mrow][ks * 32 + quad * 8];

        floatx4 acc[2][4];
        #pragma unroll
        for (int mt = 0; mt < 2; ++mt)
            #pragma unroll
            for (int nt = 0; nt < 4; ++nt)
                acc[mt][nt] = (floatx4){0.f, 0.f, 0.f, 0.f};

        #pragma unroll
        for (int nt = 0; nt < 4; ++nt) {
            #pragma unroll
            for (int ks = 0; ks < 4; ++ks) {
                half8 b = *(const half8*)&Bz[nt * 16 + mrow][ks * 32 + quad * 8];
                acc[0][nt] = __builtin_amdgcn_mfma_f32_16x16x32_f16(a[0][ks], b, acc[0][nt], 0, 0, 0);
                acc[1][nt] = __builtin_amdgcn_mfma_f32_16x16x32_f16(a[1][ks], b, acc[1][nt], 0, 0, 0);
            }
        }
        const float inv = invs_s[h];
        #pragma unroll
        for (int mt = 0; mt < 2; ++mt)
            #pragma unroll
            for (int nt = 0; nt < 4; ++nt) {
                result[mt][nt][0] += inv * acc[mt][nt][0];
                result[mt][nt][1] += inv * acc[mt][nt][1];
                result[mt][nt][2] += inv * acc[mt][nt][2];
                result[mt][nt][3] += inv * acc[mt][nt][3];
            }
        __syncthreads();
    }
    float bcol[4];
    #pragma unroll
    for (int nt = 0; nt < 4; ++nt) bcol[nt] = b_out[nt * 16 + mrow];
    #pragma unroll
    for (int mt = 0; mt < 2; ++mt) {
        #pragma unroll
        for (int r = 0; r < 4; ++r) {
            int row = m0 + w * 32 + mt * 16 + quad * 4 + r;
            if (row < N_NODES) {
                float* dst = out + (size_t)row * OUT_CH;
                #pragma unroll
                for (int nt = 0; nt < 4; ++nt)
                    dst[nt * 16 + mrow] = result[mt][nt][r] + bcol[nt];
            }
        }
    }
}

// ---------------------------------------------------------------------------
// Launch
// ---------------------------------------------------------------------------
extern "C" void kernel_launch(void* const* d_in, const int* in_sizes, int n_in,
                              void* d_out, int out_size, void* d_ws, size_t ws_size,
                              hipStream_t stream) {
    const float* x     = (const float*)d_in[0];
    const int*   ei    = (const int*)d_in[1];   // [2, E] int32
    const float* ew    = (const float*)d_in[2];
    const float* Wq    = (const float*)d_in[3];
    const float* Wk    = (const float*)d_in[4];
    const float* Wv    = (const float*)d_in[5];
    const float* We    = (const float*)d_in[6];
    const float* Wout  = (const float*)d_in[7];
    const float* b_out = (const float*)d_in[8];
    float* out = (float*)d_out;

    // workspace layout (~120 MB)
    __half* u16   = (__half*)d_ws;                          // 50000*512*2 = 51.2 MB
    __half* y16   = u16 + (size_t)N_NODES * UDIM;           // 51.2 MB
    __half* x16   = y16 + (size_t)N_NODES * UDIM;           // 12.8 MB
    double* S     = (double*)(x16 + (size_t)N_NODES * IN_CH);  // 4 doubles
    __half* M16t  = (__half*)(S + HEADS);                   // 512*128*2 = 128 KB
    __half* Zc16t = M16t + UDIM * IN_CH;                    // 64*512*2 = 64 KB
    int*    rp    = (int*)(Zc16t + OUT_CH * UDIM);          // 50000
    int*    cnt   = rp + N_NODES;                           // 50000
    int*    csum  = cnt + N_NODES;                          // 64
    int2*   payload = (int2*)(csum + 64);                   // 500000*8 = 4 MB

    prep_kernel<<<(N_NODES * IN_CH / 4 + 255) / 256, 256, 0, stream>>>(x, x16, cnt, S);
    wbuild_kernel<<<1024, 128, 0, stream>>>(Wq, Wk, Wv, Wout, M16t, Zc16t);
    gemm_u_mfma_kernel<<<dim3((N_NODES + 127) / 128, 4), 256, 0, stream>>>(x16, M16t, u16);
    hist_kernel<<<(N_EDGES + 255) / 256, 256, 0, stream>>>(ei, cnt);
    scan_reduce_kernel<<<NC, 256, 0, stream>>>(cnt, csum);
    scan_top_kernel<<<1, 64, 0, stream>>>(csum);
    scan_chunks_kernel<<<NC, 256, 0, stream>>>(cnt, csum, rp);
    scatter_kernel<<<(N_EDGES + 255) / 256, 256, 0, stream>>>(ei, ew, cnt, payload);
    edge_fused_kernel<<<N_NODES / 16, 256, 0, stream>>>(u16, x16, rp, cnt, payload, We, y16, S);
    gemm_out_mfma_kernel<<<(N_NODES + 127) / 128, 256, 0, stream>>>(y16, Zc16t, S, b_out, out);
}